// Round 7
// baseline (571.989 us; speedup 1.0000x reference)
//
#include <hip/hip_runtime.h>
#include <hip/hip_bf16.h>

// GCN: 3 x [ relu(A @ (X @ W) + b) ]  (no relu layer 3), fp32 I/O, bf16 MFMA.
// All-row-major chain (R3 proven structure):
//   G1: T  = W^T @ X^T : gemm(A=WT [F][F], BT=X [N][F]) -> T [F][N]
//   G2: X' = adj @ T^T : gemm(A=adj [N][N], BT=T [F][N]) -> X' [N][F] (+b, relu)
// NEW (R6): layer-1 G1 launches 640 threads = 8 GEMM waves + 2 CONVERTER
// waves that stream adj f32->bf16 concurrently, walking the same barrier
// skeleton (chunk-per-phase). Wave-level heterogeneity: LDS allows only one
// block/CU, but extra waves overlap HBM streaming under MFMA (m114).
// Core: 256x256 tile, BK=64, dbuf LDS, read-ahead 4-phase pipeline,
// XOR-swizzled LDS, setprio, XCD-chunked swizzle, LDS-bounced us8 epilogue.

typedef __attribute__((ext_vector_type(8))) short bf16x8s;
typedef __attribute__((ext_vector_type(4))) float f32x4;
typedef __attribute__((ext_vector_type(4))) unsigned short us4;
typedef __attribute__((ext_vector_type(8))) unsigned short us8;

__device__ __forceinline__ unsigned short f2bf(float f) {
    unsigned u = __builtin_bit_cast(unsigned, f);
    u += 0x7fffu + ((u >> 16) & 1u);          // RNE
    return (unsigned short)(u >> 16);
}

__device__ __forceinline__ void async16(const unsigned short* g, unsigned short* l) {
    __builtin_amdgcn_global_load_lds(
        (const __attribute__((address_space(1))) unsigned int*)g,
        (__attribute__((address_space(3))) unsigned int*)l, 16, 0, 0);
}

#define MFMA_(d, va, vb) d = __builtin_amdgcn_mfma_f32_16x16x32_bf16(va, vb, d, 0, 0, 0)

// ---------------- prep: x0 f32->bf16 + three W transposes ----------------
__global__ void prep(const float* __restrict__ x0, unsigned short* __restrict__ P0, long n4,
                     const float* __restrict__ W1, const float* __restrict__ W2,
                     const float* __restrict__ W3, unsigned short* __restrict__ WT1,
                     unsigned short* __restrict__ WT2, unsigned short* __restrict__ WT3,
                     int F) {
    long i = (long)blockIdx.x * blockDim.x + threadIdx.x;
    long stride = (long)gridDim.x * blockDim.x;
    for (long k = i; k < n4; k += stride) {
        float4 v = ((const float4*)x0)[k];
        us4 o;
        o.x = f2bf(v.x); o.y = f2bf(v.y); o.z = f2bf(v.z); o.w = f2bf(v.w);
        ((us4*)P0)[k] = o;
    }
    const long FF = (long)F * F;
    for (long k = i; k < 3 * FF; k += stride) {
        int w = (int)(k / FF);
        long idx = k % FF;
        int r = (int)(idx % F);
        int c = (int)(idx / F);
        const float* W = (w == 0) ? W1 : (w == 1) ? W2 : W3;
        unsigned short* WT = (w == 0) ? WT1 : (w == 1) ? WT2 : WT3;
        WT[idx] = f2bf(W[(size_t)r * F + c]);
    }
}

// ---------------- batched GEMM C = A @ B,  B given transposed ----------------
// A : bf16 [bat][M][K] (sA==0 -> shared); BT : bf16 [bat][N][K]
// Out row-major [bat][M][N].
// CVTW: block has 2 extra waves (t>=512) that convert this block's adj slice
// f32->bf16 in 32 chunks, one per barrier phase (same barrier count as GEMM).
template<bool RELU, bool OUT_F32, bool CVTW>
__global__ __launch_bounds__(CVTW ? 640 : 512, CVTW ? 1 : 2)
void gemm256(const unsigned short* __restrict__ A,
             const unsigned short* __restrict__ BT,
             void* __restrict__ Cout,
             const float* __restrict__ bias,
             int M, int N, int K,
             long sA, long sBT, long sC,
             const float* __restrict__ adjf,
             unsigned short* __restrict__ adjb)
{
    __shared__ unsigned short Lraw[65536];     // 128 KiB: A dbuf | B dbuf

    const int t    = threadIdx.x;
    const int lane = t & 63;
    const int wv   = t >> 6;
    const bool isCvt = CVTW && (t >= 512);
    const int wm   = wv >> 2;
    const int wn   = wv & 3;
    const int fr   = lane & 15;
    const int fk   = (lane >> 4) * 8;
    const int r4   = (lane >> 4) * 4;

    const int tilesN = N >> 8;
    const int bpb    = (M >> 8) * tilesN;
    const int cpx = gridDim.x >> 3;    // grid divisible by 8 -> bijective
    const int lb  = (blockIdx.x & 7) * cpx + (blockIdx.x >> 3);
    const int bat = lb / bpb;
    const int tt  = lb % bpb;
    const int m0  = (tt / tilesN) << 8;
    const int n0  = (tt % tilesN) << 8;

    const unsigned short* Ab = A  + (size_t)bat * sA  + (size_t)m0 * K;
    const unsigned short* Bb = BT + (size_t)bat * sBT + (size_t)n0 * K;

    int srow[2], scol[2], lo[2];
#pragma unroll
    for (int r = 0; r < 2; ++r) {
        int c   = r * 512 + (t & 511);
        srow[r] = c >> 3;
        scol[r] = ((c & 7) * 8) ^ ((srow[r] & 7) << 3);
        lo[r]   = c * 8;
    }

    auto stageA = [&](int kt, int h) {
        unsigned short* base = Lraw + (kt & 1) * 16384;
#pragma unroll
        for (int r = 0; r < 2; ++r)
            async16(Ab + (size_t)(h * 128 + srow[r]) * K + kt * 64 + scol[r],
                    base + h * 8192 + lo[r]);
    };
    auto stageB = [&](int kt, int h) {
        unsigned short* base = Lraw + 32768 + (kt & 1) * 16384;
#pragma unroll
        for (int r = 0; r < 2; ++r)
            async16(Bb + (size_t)(h * 128 + srow[r]) * K + kt * 64 + scol[r],
                    base + h * 8192 + lo[r]);
    };
    auto rdA = [&](int buf, int mf, int kkj) -> bf16x8s {
        int row = wm * 128 + mf * 16 + fr;
        int e   = (kkj * 32 + fk) ^ ((row & 7) << 3);
        return *(const bf16x8s*)&Lraw[buf * 16384 + row * 64 + e];
    };
    auto rdB = [&](int buf, int nf, int kkj) -> bf16x8s {
        int row = wn * 64 + nf * 16 + fr;
        int e   = (kkj * 32 + fk) ^ ((row & 7) << 3);
        return *(const bf16x8s*)&Lraw[32768 + buf * 16384 + row * 64 + e];
    };

    // converter-wave chunk: 512 float4 per wave per chunk (8 per lane)
    auto cvtChunk = [&](int c) {
        if constexpr (CVTW) {
            const long base = (long)(lb >> 3) * 262144 + (long)(lb & 7) * 32768
                            + (long)(wv - 8) * 16384 + (long)c * 512 + lane;
            const float4* src = (const float4*)adjf;
            us4* dst = (us4*)adjb;
#pragma unroll
            for (int k = 0; k < 8; ++k) {
                float4 v = src[base + k * 64];
                us4 o;
                o.x = f2bf(v.x); o.y = f2bf(v.y); o.z = f2bf(v.z); o.w = f2bf(v.w);
                dst[base + k * 64] = o;
            }
        }
    };

    const int nt = K >> 6;

    f32x4 acc[8][4];
#pragma unroll
    for (int i = 0; i < 8; ++i)
#pragma unroll
        for (int j = 0; j < 4; ++j) acc[i][j] = f32x4{0.f, 0.f, 0.f, 0.f};

    bf16x8s aP[4], aB[4], aC[4], bX[4], bY[4];

    // ---- prologue: stage tile0; read (m0-3,k0) + B(k0) ----
    if (!isCvt) {
        stageA(0, 0); stageB(0, 0); stageA(0, 1); stageB(0, 1);
        asm volatile("s_waitcnt vmcnt(0)" ::: "memory");
    }
    __builtin_amdgcn_s_barrier();
    if (!isCvt) {
#pragma unroll
        for (int m = 0; m < 4; ++m) aP[m] = rdA(0, m, 0);
#pragma unroll
        for (int n = 0; n < 4; ++n) bX[n] = rdB(0, n, 0);
    }

    for (int it = 0; it < nt; ++it) {
        const int cur  = it & 1;
        const int nxt  = cur ^ 1;
        const bool more = (it + 1 < nt);

        // ph0: MFMA m0-3 x k0; read A(m4-7,k0); stage h0 of t+1
        __builtin_amdgcn_s_barrier();
        if (!isCvt) {
#pragma unroll
            for (int m = 0; m < 4; ++m) aB[m] = rdA(cur, m + 4, 0);
            if (more) { stageA(it + 1, 0); stageB(it + 1, 0); }
            __builtin_amdgcn_s_setprio(1);
#pragma unroll
            for (int m = 0; m < 4; ++m)
#pragma unroll
                for (int n = 0; n < 4; ++n) MFMA_(acc[m][n], aP[m], bX[n]);
            __builtin_amdgcn_s_setprio(0);
        } else cvtChunk(it * 4 + 0);

        // ph1: MFMA m4-7 x k0; read A(m0-3,k1)+B(k1); stage h1 of t+1
        __builtin_amdgcn_s_barrier();
        if (!isCvt) {
#pragma unroll
            for (int m = 0; m < 4; ++m) aC[m] = rdA(cur, m, 1);
#pragma unroll
            for (int n = 0; n < 4; ++n) bY[n] = rdB(cur, n, 1);
            if (more) { stageA(it + 1, 1); stageB(it + 1, 1); }
            __builtin_amdgcn_s_setprio(1);
#pragma unroll
            for (int m = 0; m < 4; ++m)
#pragma unroll
                for (int n = 0; n < 4; ++n) MFMA_(acc[m + 4][n], aB[m], bX[n]);
            __builtin_amdgcn_s_setprio(0);
        } else cvtChunk(it * 4 + 1);

        // ph2: MFMA m0-3 x k1; read A(m4-7,k1)
        __builtin_amdgcn_s_barrier();
        if (!isCvt) {
#pragma unroll
            for (int m = 0; m < 4; ++m) aB[m] = rdA(cur, m + 4, 1);
            __builtin_amdgcn_s_setprio(1);
#pragma unroll
            for (int m = 0; m < 4; ++m)
#pragma unroll
                for (int n = 0; n < 4; ++n) MFMA_(acc[m][n], aC[m], bY[n]);
            __builtin_amdgcn_s_setprio(0);
        } else cvtChunk(it * 4 + 2);

        // ph3: t+1 visibility; read next (m0-3,k0)+B(k0); MFMA m4-7 x k1
        if (!isCvt && more) asm volatile("s_waitcnt vmcnt(0)" ::: "memory");
        __builtin_amdgcn_s_barrier();
        if (!isCvt) {
            if (more) {
#pragma unroll
                for (int m = 0; m < 4; ++m) aP[m] = rdA(nxt, m, 0);
#pragma unroll
                for (int n = 0; n < 4; ++n) bX[n] = rdB(nxt, n, 0);
            }
            __builtin_amdgcn_s_setprio(1);
#pragma unroll
            for (int m = 0; m < 4; ++m)
#pragma unroll
                for (int n = 0; n < 4; ++n) MFMA_(acc[m + 4][n], aB[m], bY[n]);
            __builtin_amdgcn_s_setprio(0);
        } else cvtChunk(it * 4 + 3);
    }

    __syncthreads();   // K-loop LDS reads done before epilogue reuses LDS

    // ---------------- epilogue (GEMM waves only): row-major C [M][N] --------
    if (!isCvt) {
        const int R0 = m0 + wm * 128;
        const int C0 = n0 + wn * 64;
        float bv[4];
#pragma unroll
        for (int j = 0; j < 4; ++j)
            bv[j] = bias ? bias[C0 + j * 16 + fr] : 0.f;

        if (OUT_F32) {
            float* Cb = (float*)Cout + (size_t)bat * sC;
#pragma unroll
            for (int j = 0; j < 4; ++j)
#pragma unroll
                for (int i = 0; i < 8; ++i)
#pragma unroll
                    for (int e = 0; e < 4; ++e) {
                        float v = acc[i][j][e] + bv[j];
                        if (RELU) v = fmaxf(v, 0.f);
                        Cb[(size_t)(R0 + i * 16 + r4 + e) * N + C0 + j * 16 + fr] = v;
                    }
        } else {
            unsigned short* sl = Lraw + wv * 8192;
#pragma unroll
            for (int i = 0; i < 8; ++i)
#pragma unroll
                for (int j = 0; j < 4; ++j)
#pragma unroll
                    for (int e = 0; e < 4; ++e) {
                        float v = acc[i][j][e] + bv[j];
                        if (RELU) v = fmaxf(v, 0.f);
                        const int row = i * 16 + r4 + e;
                        const int col = j * 16 + fr;
                        sl[row * 64 + (col ^ ((row & 7) << 3))] = f2bf(v);
                    }
            unsigned short* Cb = (unsigned short*)Cout + (size_t)bat * sC;
#pragma unroll
            for (int rr = 0; rr < 16; ++rr) {
                const int row = rr * 8 + (lane >> 3);
                const int k8  = lane & 7;
                us8 v = *(const us8*)&sl[row * 64 + ((k8 ^ (row & 7)) << 3)];
                *(us8*)&Cb[(size_t)(R0 + row) * N + C0 + k8 * 8] = v;
            }
        }
    }
}

extern "C" void kernel_launch(void* const* d_in, const int* in_sizes, int n_in,
                              void* d_out, int out_size, void* d_ws, size_t ws_size,
                              hipStream_t stream) {
    constexpr int B = 32, N = 1024, F = 512;

    const float* x0f  = (const float*)d_in[0];
    const float* adjf = (const float*)d_in[1];
    const float* W1 = (const float*)d_in[2];
    const float* b1 = (const float*)d_in[3];
    const float* W2 = (const float*)d_in[4];
    const float* b2 = (const float*)d_in[5];
    const float* W3 = (const float*)d_in[6];
    const float* b3 = (const float*)d_in[7];

    unsigned short* ws   = (unsigned short*)d_ws;
    unsigned short* adjb = ws;                           // B*N*N
    unsigned short* P0   = adjb + (size_t)B * N * N;     // B*N*F  (X buffers)
    unsigned short* P1   = P0 + (size_t)B * N * F;
    unsigned short* PT   = P1 + (size_t)B * N * F;       // B*F*N  (T buffer)
    unsigned short* WT1  = PT + (size_t)B * N * F;
    unsigned short* WT2  = WT1 + (size_t)F * F;
    unsigned short* WT3  = WT2 + (size_t)F * F;

    prep<<<2048, 256, 0, stream>>>(x0f, P0, (long)B * N * F / 4,
                                   W1, W2, W3, WT1, WT2, WT3, F);

    const int grid = 256;                 // both GEMM shapes: 32 bat x 8 tiles
    const long sX = (long)N * F;
    const long sAd = (long)N * N;

    // layer 1 (G1 carries 2 converter waves streaming adj f32->bf16)
    gemm256<false, false, true ><<<grid, 640, 0, stream>>>(WT1,  P0, PT, nullptr, F, N, F, 0,  sX, sX, adjf, adjb);
    gemm256<true,  false, false><<<grid, 512, 0, stream>>>(adjb, PT, P1, b1,      N, F, N, sAd, sX, sX, nullptr, nullptr);
    // layer 2
    gemm256<false, false, false><<<grid, 512, 0, stream>>>(WT2,  P1, PT, nullptr, F, N, F, 0,  sX, sX, nullptr, nullptr);
    gemm256<true,  false, false><<<grid, 512, 0, stream>>>(adjb, PT, P0, b2,      N, F, N, sAd, sX, sX, nullptr, nullptr);
    // layer 3 (fp32 out, no relu)
    gemm256<false, false, false><<<grid, 512, 0, stream>>>(WT3,  P0, PT, nullptr, F, N, F, 0,  sX, sX, nullptr, nullptr);
    gemm256<false, true,  false><<<grid, 512, 0, stream>>>(adjb, PT, (float*)d_out, b3, N, F, N, sAd, sX, sX, nullptr, nullptr);
}

// Round 8
// 565.786 us; speedup vs baseline: 1.0110x; 1.0110x over previous
//
#include <hip/hip_runtime.h>
#include <hip/hip_bf16.h>

// GCN: 3 x [ relu(A @ (X @ W) + b) ]  (no relu layer 3), fp32 I/O, bf16 MFMA.
// MEGA-KERNEL v2: 256 blocks (1/CU, co-resident), all 6 GEMMs + adj cvt in one
// dispatch. Every core call is FULLY template-specialized (R4's spill came from
// runtime-parameterized cores); waits/releases only BETWEEN cores.
// All dataflow is batch-local (batch b's 8 blocks <-> one XCD): per-batch flags
//   g1done[l][bat][half] (4 producers per PT-half), cvtdone[bat], g2done[l][bat].
// Core: 256x256 tile, BK=64, 8 waves (2Mx4N), dbuf LDS, read-ahead 4-phase
// pipeline, XOR-swizzled LDS, setprio, LDS-bounced us8 epilogue (R3-proven).

typedef __attribute__((ext_vector_type(8))) short bf16x8s;
typedef __attribute__((ext_vector_type(4))) float f32x4;
typedef __attribute__((ext_vector_type(4))) unsigned short us4;
typedef __attribute__((ext_vector_type(8))) unsigned short us8;

__device__ __forceinline__ unsigned short f2bf(float f) {
    unsigned u = __builtin_bit_cast(unsigned, f);
    u += 0x7fffu + ((u >> 16) & 1u);          // RNE
    return (unsigned short)(u >> 16);
}

__device__ __forceinline__ void async16(const unsigned short* g, unsigned short* l) {
    __builtin_amdgcn_global_load_lds(
        (const __attribute__((address_space(1))) unsigned int*)g,
        (__attribute__((address_space(3))) unsigned int*)l, 16, 0, 0);
}

#define MFMA_(d, va, vb) d = __builtin_amdgcn_mfma_f32_16x16x32_bf16(va, vb, d, 0, 0, 0)

// ---------------- sync-state zero (every launch; replay-safe) ----------------
__global__ void zero_sync(unsigned* s, int n) {
    for (int i = threadIdx.x; i < n; i += 256) s[i] = 0;
}

// ---------------- prep: x0 f32->bf16 + three W transposes ----------------
__global__ void prep(const float* __restrict__ x0, unsigned short* __restrict__ P0, long n4,
                     const float* __restrict__ W1, const float* __restrict__ W2,
                     const float* __restrict__ W3, unsigned short* __restrict__ WT1,
                     unsigned short* __restrict__ WT2, unsigned short* __restrict__ WT3,
                     int F) {
    long i = (long)blockIdx.x * blockDim.x + threadIdx.x;
    long stride = (long)gridDim.x * blockDim.x;
    for (long k = i; k < n4; k += stride) {
        float4 v = ((const float4*)x0)[k];
        us4 o;
        o.x = f2bf(v.x); o.y = f2bf(v.y); o.z = f2bf(v.z); o.w = f2bf(v.w);
        ((us4*)P0)[k] = o;
    }
    const long FF = (long)F * F;
    for (long k = i; k < 3 * FF; k += stride) {
        int w = (int)(k / FF);
        long idx = k % FF;
        int r = (int)(idx % F);
        int c = (int)(idx / F);
        const float* W = (w == 0) ? W1 : (w == 1) ? W2 : W3;
        unsigned short* WT = (w == 0) ? WT1 : (w == 1) ? WT2 : WT3;
        WT[idx] = f2bf(W[(size_t)r * F + c]);
    }
}

// ---------------- flag helpers (block-uniform, between cores only) ----------
__device__ __forceinline__ void relf(unsigned* p, int t) {
    asm volatile("s_waitcnt vmcnt(0)" ::: "memory");   // this wave's stores done
    __syncthreads();                                   // all waves' stores done
    if (t == 0)
        __hip_atomic_fetch_add(p, 1u, __ATOMIC_RELEASE, __HIP_MEMORY_SCOPE_AGENT);
}
__device__ __forceinline__ void waitf(unsigned* p, unsigned tgt, int t) {
    if (t == 0) {
        while (__hip_atomic_load(p, __ATOMIC_ACQUIRE, __HIP_MEMORY_SCOPE_AGENT) < tgt)
            __builtin_amdgcn_s_sleep(8);
    }
    __syncthreads();
    __builtin_amdgcn_sched_barrier(0);
}

// ---------------- GEMM core (fully static shape) ----------------
// C[MM][NN] = A[MM][KK] @ BT[NN][KK]^T ; 8 tiles/batch (MM/256 * NN/256 == 8).
template<int MM, int NN, int KK, int LGTN, bool RELU, bool OUTF32>
__device__ __forceinline__ void core(
    unsigned short* Lraw, int lb,
    const unsigned short* __restrict__ A,
    const unsigned short* __restrict__ BT,
    void* __restrict__ Cout, const float* __restrict__ bias,
    long sA, long sBT, long sC)
{
    static_assert((MM / 256) * (NN / 256) == 8, "8 tiles per batch");
    const int t    = threadIdx.x;
    const int lane = t & 63;
    const int wv   = t >> 6;
    const int wm   = wv >> 2;
    const int wn   = wv & 3;
    const int fr   = lane & 15;
    const int fk   = (lane >> 4) * 8;
    const int r4   = (lane >> 4) * 4;

    const int bat = lb >> 3;
    const int tt  = lb & 7;
    const int m0  = (tt >> LGTN) << 8;
    const int n0  = (tt & ((1 << LGTN) - 1)) << 8;

    const unsigned short* Ab = A  + (size_t)bat * sA  + (size_t)m0 * KK;
    const unsigned short* Bb = BT + (size_t)bat * sBT + (size_t)n0 * KK;

    int srow[2], scol[2], lo[2];
#pragma unroll
    for (int r = 0; r < 2; ++r) {
        int c   = r * 512 + t;
        srow[r] = c >> 3;
        scol[r] = ((c & 7) * 8) ^ ((srow[r] & 7) << 3);
        lo[r]   = c * 8;
    }

    auto stageA = [&](int kt, int h) {
        unsigned short* base = Lraw + (kt & 1) * 16384;
#pragma unroll
        for (int r = 0; r < 2; ++r)
            async16(Ab + (size_t)(h * 128 + srow[r]) * KK + kt * 64 + scol[r],
                    base + h * 8192 + lo[r]);
    };
    auto stageB = [&](int kt, int h) {
        unsigned short* base = Lraw + 32768 + (kt & 1) * 16384;
#pragma unroll
        for (int r = 0; r < 2; ++r)
            async16(Bb + (size_t)(h * 128 + srow[r]) * KK + kt * 64 + scol[r],
                    base + h * 8192 + lo[r]);
    };
    auto rdA = [&](int buf, int mf, int kkj) -> bf16x8s {
        int row = wm * 128 + mf * 16 + fr;
        int e   = (kkj * 32 + fk) ^ ((row & 7) << 3);
        return *(const bf16x8s*)&Lraw[buf * 16384 + row * 64 + e];
    };
    auto rdB = [&](int buf, int nf, int kkj) -> bf16x8s {
        int row = wn * 64 + nf * 16 + fr;
        int e   = (kkj * 32 + fk) ^ ((row & 7) << 3);
        return *(const bf16x8s*)&Lraw[32768 + buf * 16384 + row * 64 + e];
    };

    constexpr int nt = KK >> 6;

    f32x4 acc[8][4];
#pragma unroll
    for (int i = 0; i < 8; ++i)
#pragma unroll
        for (int j = 0; j < 4; ++j) acc[i][j] = f32x4{0.f, 0.f, 0.f, 0.f};

    bf16x8s aP[4], aB[4], aC[4], bX[4], bY[4];

    stageA(0, 0); stageB(0, 0); stageA(0, 1); stageB(0, 1);
    asm volatile("s_waitcnt vmcnt(0)" ::: "memory");
    __builtin_amdgcn_s_barrier();
#pragma unroll
    for (int m = 0; m < 4; ++m) aP[m] = rdA(0, m, 0);
#pragma unroll
    for (int n = 0; n < 4; ++n) bX[n] = rdB(0, n, 0);

    for (int it = 0; it < nt; ++it) {
        const int cur  = it & 1;
        const int nxt  = cur ^ 1;
        const bool more = (it + 1 < nt);

        // ph0: MFMA m0-3 x k0; read A(m4-7,k0); stage h0 of t+1
        __builtin_amdgcn_s_barrier();
#pragma unroll
        for (int m = 0; m < 4; ++m) aB[m] = rdA(cur, m + 4, 0);
        if (more) { stageA(it + 1, 0); stageB(it + 1, 0); }
        __builtin_amdgcn_s_setprio(1);
#pragma unroll
        for (int m = 0; m < 4; ++m)
#pragma unroll
            for (int n = 0; n < 4; ++n) MFMA_(acc[m][n], aP[m], bX[n]);
        __builtin_amdgcn_s_setprio(0);

        // ph1: MFMA m4-7 x k0; read A(m0-3,k1)+B(k1); stage h1 of t+1
        __builtin_amdgcn_s_barrier();
#pragma unroll
        for (int m = 0; m < 4; ++m) aC[m] = rdA(cur, m, 1);
#pragma unroll
        for (int n = 0; n < 4; ++n) bY[n] = rdB(cur, n, 1);
        if (more) { stageA(it + 1, 1); stageB(it + 1, 1); }
        __builtin_amdgcn_s_setprio(1);
#pragma unroll
        for (int m = 0; m < 4; ++m)
#pragma unroll
            for (int n = 0; n < 4; ++n) MFMA_(acc[m + 4][n], aB[m], bX[n]);
        __builtin_amdgcn_s_setprio(0);

        // ph2: MFMA m0-3 x k1; read A(m4-7,k1)
        __builtin_amdgcn_s_barrier();
#pragma unroll
        for (int m = 0; m < 4; ++m) aB[m] = rdA(cur, m + 4, 1);
        __builtin_amdgcn_s_setprio(1);
#pragma unroll
        for (int m = 0; m < 4; ++m)
#pragma unroll
            for (int n = 0; n < 4; ++n) MFMA_(acc[m][n], aC[m], bY[n]);
        __builtin_amdgcn_s_setprio(0);

        // ph3: t+1 visibility; read next (m0-3,k0)+B(k0); MFMA m4-7 x k1
        if (more) {
            asm volatile("s_waitcnt vmcnt(0)" ::: "memory");
            __builtin_amdgcn_s_barrier();
#pragma unroll
            for (int m = 0; m < 4; ++m) aP[m] = rdA(nxt, m, 0);
#pragma unroll
            for (int n = 0; n < 4; ++n) bX[n] = rdB(nxt, n, 0);
        }
        __builtin_amdgcn_s_setprio(1);
#pragma unroll
        for (int m = 0; m < 4; ++m)
#pragma unroll
            for (int n = 0; n < 4; ++n) MFMA_(acc[m + 4][n], aB[m], bY[n]);
        __builtin_amdgcn_s_setprio(0);
    }

    __syncthreads();   // K-loop LDS reads done before epilogue reuses LDS

    const int R0 = m0 + wm * 128;
    const int C0 = n0 + wn * 64;
    float bv[4];
#pragma unroll
    for (int j = 0; j < 4; ++j)
        bv[j] = bias ? bias[C0 + j * 16 + fr] : 0.f;

    if (OUTF32) {
        float* Cb = (float*)Cout + (size_t)bat * sC;
#pragma unroll
        for (int j = 0; j < 4; ++j)
#pragma unroll
            for (int i = 0; i < 8; ++i)
#pragma unroll
                for (int e = 0; e < 4; ++e) {
                    float v = acc[i][j][e] + bv[j];
                    if (RELU) v = fmaxf(v, 0.f);
                    Cb[(size_t)(R0 + i * 16 + r4 + e) * NN + C0 + j * 16 + fr] = v;
                }
    } else {
        unsigned short* sl = Lraw + wv * 8192;
#pragma unroll
        for (int i = 0; i < 8; ++i)
#pragma unroll
            for (int j = 0; j < 4; ++j)
#pragma unroll
                for (int e = 0; e < 4; ++e) {
                    float v = acc[i][j][e] + bv[j];
                    if (RELU) v = fmaxf(v, 0.f);
                    const int row = i * 16 + r4 + e;
                    const int col = j * 16 + fr;
                    sl[row * 64 + (col ^ ((row & 7) << 3))] = f2bf(v);
                }
        unsigned short* Cb = (unsigned short*)Cout + (size_t)bat * sC;
#pragma unroll
        for (int rr = 0; rr < 16; ++rr) {
            const int row = rr * 8 + (lane >> 3);
            const int k8  = lane & 7;
            us8 v = *(const us8*)&sl[row * 64 + ((k8 ^ (row & 7)) << 3)];
            *(us8*)&Cb[(size_t)(R0 + row) * NN + C0 + k8 * 8] = v;
        }
    }
    __syncthreads();   // LDS-bounce reads done before next core's staging (WAR)
}

// ---------------- adj slice convert (block-local, between cores) -----------
__device__ __forceinline__ void cvt_slice(const float* __restrict__ adjf,
                                          unsigned short* __restrict__ adjb,
                                          int lb, int t) {
    const int bat = lb >> 3, s = lb & 7;
    const float4* src = (const float4*)adjf + ((size_t)bat * 262144 + (size_t)s * 32768);
    us4* dst = (us4*)adjb + ((size_t)bat * 262144 + (size_t)s * 32768);
#pragma unroll 4
    for (int i = t; i < 32768; i += 512) {
        float4 v = src[i];
        us4 o;
        o.x = f2bf(v.x); o.y = f2bf(v.y); o.z = f2bf(v.z); o.w = f2bf(v.w);
        dst[i] = o;
    }
}

// ---------------- mega: all 6 GEMMs + cvt, per-batch pipelined --------------
__global__ __launch_bounds__(512, 2)
void mega(const float* __restrict__ adjf,
          unsigned short* __restrict__ adjb,
          unsigned short* __restrict__ P0, unsigned short* __restrict__ P1,
          unsigned short* __restrict__ PT,
          const unsigned short* __restrict__ WT1, const unsigned short* __restrict__ WT2,
          const unsigned short* __restrict__ WT3,
          const float* __restrict__ b1, const float* __restrict__ b2,
          const float* __restrict__ b3,
          float* __restrict__ dout,
          unsigned* __restrict__ sync)
{
    __shared__ unsigned short Lraw[65536];

    const int t  = threadIdx.x;
    const int lb = ((int)blockIdx.x & 7) * 32 + ((int)blockIdx.x >> 3);
    const int bat = lb >> 3;
    const int tt  = lb & 7;

    unsigned* g1d  = sync;              // [3][32][2]
    unsigned* cvtd = sync + 192;        // [32]
    unsigned* g2d  = sync + 224;        // [2][32]

    const long sX  = 1024L * 512;
    const long sAd = 1024L * 1024;

    // ---------------- layer 1 ----------------
    core<512, 1024, 512, 2, false, false>(Lraw, lb, WT1, P0, PT, nullptr, 0, sX, sX);
    relf(&g1d[(0 * 32 + bat) * 2 + (tt >> 2)], t);

    cvt_slice(adjf, adjb, lb, t);
    relf(&cvtd[bat], t);

    waitf(&g1d[(0 * 32 + bat) * 2 + (tt & 1)], 4, t);
    waitf(&cvtd[bat], 8, t);
    core<1024, 512, 1024, 1, true, false>(Lraw, lb, adjb, PT, P1, b1, sAd, sX, sX);
    relf(&g2d[0 * 32 + bat], t);

    // ---------------- layer 2 ----------------
    waitf(&g2d[0 * 32 + bat], 8, t);    // P1[bat] complete; PT[bat] free (WAR)
    core<512, 1024, 512, 2, false, false>(Lraw, lb, WT2, P1, PT, nullptr, 0, sX, sX);
    relf(&g1d[(1 * 32 + bat) * 2 + (tt >> 2)], t);

    waitf(&g1d[(1 * 32 + bat) * 2 + (tt & 1)], 4, t);
    core<1024, 512, 1024, 1, true, false>(Lraw, lb, adjb, PT, P0, b2, sAd, sX, sX);
    relf(&g2d[1 * 32 + bat], t);

    // ---------------- layer 3 ----------------
    waitf(&g2d[1 * 32 + bat], 8, t);
    core<512, 1024, 512, 2, false, false>(Lraw, lb, WT3, P0, PT, nullptr, 0, sX, sX);
    relf(&g1d[(2 * 32 + bat) * 2 + (tt >> 2)], t);

    waitf(&g1d[(2 * 32 + bat) * 2 + (tt & 1)], 4, t);
    core<1024, 512, 1024, 1, false, true>(Lraw, lb, adjb, PT, dout, b3, sAd, sX, sX);
}

extern "C" void kernel_launch(void* const* d_in, const int* in_sizes, int n_in,
                              void* d_out, int out_size, void* d_ws, size_t ws_size,
                              hipStream_t stream) {
    constexpr int B = 32, N = 1024, F = 512;

    const float* x0f  = (const float*)d_in[0];
    const float* adjf = (const float*)d_in[1];
    const float* W1 = (const float*)d_in[2];
    const float* b1 = (const float*)d_in[3];
    const float* W2 = (const float*)d_in[4];
    const float* b2 = (const float*)d_in[5];
    const float* W3 = (const float*)d_in[6];
    const float* b3 = (const float*)d_in[7];

    unsigned short* ws   = (unsigned short*)d_ws;
    unsigned short* adjb = ws;                           // B*N*N
    unsigned short* P0   = adjb + (size_t)B * N * N;
    unsigned short* P1   = P0 + (size_t)B * N * F;
    unsigned short* PT   = P1 + (size_t)B * N * F;
    unsigned short* WT1  = PT + (size_t)B * N * F;
    unsigned short* WT2  = WT1 + (size_t)F * F;
    unsigned short* WT3  = WT2 + (size_t)F * F;
    unsigned* sync       = (unsigned*)(WT3 + (size_t)F * F);
    constexpr int SYNC_WORDS = 192 + 32 + 64;

    zero_sync<<<1, 256, 0, stream>>>(sync, SYNC_WORDS);
    prep<<<2048, 256, 0, stream>>>(x0f, P0, (long)B * N * F / 4,
                                   W1, W2, W3, WT1, WT2, WT3, F);
    mega<<<256, 512, 0, stream>>>(adjf, adjb, P0, P1, PT, WT1, WT2, WT3,
                                  b1, b2, b3, (float*)d_out, sync);
}

// Round 9
// 256.041 us; speedup vs baseline: 2.2340x; 2.2097x over previous
//
#include <hip/hip_runtime.h>
#include <hip/hip_bf16.h>

// GCN: 3 x [ relu(A @ (X @ W) + b) ]  (no relu layer 3), fp32 I/O, bf16 MFMA.
// All-row-major chain (R3 proven structure, separate dispatches):
//   G1: T  = W^T @ X^T : gemm(A=WT [F][F], BT=X [N][F]) -> T [F][N]
//   G2: X' = adj @ T^T : gemm(A=adj [N][N], BT=T [F][N]) -> X' [N][F] (+b, relu)
// R8: deeper staging pipeline to beat the per-CU MLP ceiling (~21 GB/s/CU):
//   LDS 160KB: A double-buffered (2x32KB) + B TRIPLE-buffered (3x32KB).
//   B staged 2 tiles ahead; counted s_waitcnt vmcnt(4) (never 0 in steady
//   state) keeps ~2x staged bytes in flight. prep absorbs the adj f32->bf16
//   convert (one streaming dispatch). Core frag schedule unchanged from R3.

typedef __attribute__((ext_vector_type(8))) short bf16x8s;
typedef __attribute__((ext_vector_type(4))) float f32x4;
typedef __attribute__((ext_vector_type(4))) unsigned short us4;
typedef __attribute__((ext_vector_type(8))) unsigned short us8;

__device__ __forceinline__ unsigned short f2bf(float f) {
    unsigned u = __builtin_bit_cast(unsigned, f);
    u += 0x7fffu + ((u >> 16) & 1u);          // RNE
    return (unsigned short)(u >> 16);
}

__device__ __forceinline__ void async16(const unsigned short* g, unsigned short* l) {
    __builtin_amdgcn_global_load_lds(
        (const __attribute__((address_space(1))) unsigned int*)g,
        (__attribute__((address_space(3))) unsigned int*)l, 16, 0, 0);
}

#define MFMA_(d, va, vb) d = __builtin_amdgcn_mfma_f32_16x16x32_bf16(va, vb, d, 0, 0, 0)

// -------- prep: x0 f32->bf16 + adj f32->bf16 + three W transposes --------
__global__ void prep(const float* __restrict__ x0, unsigned short* __restrict__ P0, long n4,
                     const float* __restrict__ adjf, unsigned short* __restrict__ adjb, long na4,
                     const float* __restrict__ W1, const float* __restrict__ W2,
                     const float* __restrict__ W3, unsigned short* __restrict__ WT1,
                     unsigned short* __restrict__ WT2, unsigned short* __restrict__ WT3,
                     int F) {
    long i = (long)blockIdx.x * blockDim.x + threadIdx.x;
    long stride = (long)gridDim.x * blockDim.x;
    for (long k = i; k < na4; k += stride) {
        float4 v = ((const float4*)adjf)[k];
        us4 o;
        o.x = f2bf(v.x); o.y = f2bf(v.y); o.z = f2bf(v.z); o.w = f2bf(v.w);
        ((us4*)adjb)[k] = o;
    }
    for (long k = i; k < n4; k += stride) {
        float4 v = ((const float4*)x0)[k];
        us4 o;
        o.x = f2bf(v.x); o.y = f2bf(v.y); o.z = f2bf(v.z); o.w = f2bf(v.w);
        ((us4*)P0)[k] = o;
    }
    const long FF = (long)F * F;
    for (long k = i; k < 3 * FF; k += stride) {
        int w = (int)(k / FF);
        long idx = k % FF;
        int r = (int)(idx % F);
        int c = (int)(idx / F);
        const float* W = (w == 0) ? W1 : (w == 1) ? W2 : W3;
        unsigned short* WT = (w == 0) ? WT1 : (w == 1) ? WT2 : WT3;
        WT[idx] = f2bf(W[(size_t)r * F + c]);
    }
}

// ---------------- batched GEMM C = A @ B,  B given transposed ----------------
// A : bf16 [bat][M][K] (sA==0 -> shared); BT : bf16 [bat][N][K]
// Out row-major [bat][M][N]; bias by col (nullptr ok); optional relu/f32.
template<bool RELU, bool OUT_F32>
__global__ __launch_bounds__(512, 2)
void gemm256(const unsigned short* __restrict__ A,
             const unsigned short* __restrict__ BT,
             void* __restrict__ Cout,
             const float* __restrict__ bias,
             int M, int N, int K,
             long sA, long sBT, long sC)
{
    // 160 KiB LDS: A dbuf [0, 32K elems) ; B tripbuf [32K, 80K elems)
    __shared__ unsigned short Lraw[81920];

    const int t    = threadIdx.x;
    const int lane = t & 63;
    const int wv   = t >> 6;
    const int wm   = wv >> 2;          // 0..1  -> 128-row half
    const int wn   = wv & 3;           // 0..3  -> 64-col strip
    const int fr   = lane & 15;
    const int fk   = (lane >> 4) * 8;
    const int r4   = (lane >> 4) * 4;

    const int tilesN = N >> 8;
    const int bpb    = (M >> 8) * tilesN;
    const int cpx = gridDim.x >> 3;    // grid divisible by 8 -> bijective
    const int lb  = (blockIdx.x & 7) * cpx + (blockIdx.x >> 3);
    const int bat = lb / bpb;
    const int tt  = lb % bpb;
    const int m0  = (tt / tilesN) << 8;
    const int n0  = (tt % tilesN) << 8;

    const unsigned short* Ab = A  + (size_t)bat * sA  + (size_t)m0 * K;
    const unsigned short* Bb = BT + (size_t)bat * sBT + (size_t)n0 * K;

    // staging: chunk c = r*512+t -> LDS elems [c*8, c*8+8) of a 128-row half
    int srow[2], scol[2], lo[2];
#pragma unroll
    for (int r = 0; r < 2; ++r) {
        int c   = r * 512 + t;
        srow[r] = c >> 3;
        scol[r] = ((c & 7) * 8) ^ ((srow[r] & 7) << 3);
        lo[r]   = c * 8;
    }

    auto stageA = [&](int kt, int h) {              // 2 instrs
        unsigned short* base = Lraw + (kt & 1) * 16384;
#pragma unroll
        for (int r = 0; r < 2; ++r)
            async16(Ab + (size_t)(h * 128 + srow[r]) * K + kt * 64 + scol[r],
                    base + h * 8192 + lo[r]);
    };
    auto stageB = [&](int buf, int kt) {            // both halves, 4 instrs
        unsigned short* base = Lraw + 32768 + buf * 16384;
#pragma unroll
        for (int h = 0; h < 2; ++h)
#pragma unroll
            for (int r = 0; r < 2; ++r)
                async16(Bb + (size_t)(h * 128 + srow[r]) * K + kt * 64 + scol[r],
                        base + h * 8192 + lo[r]);
    };
    auto rdA = [&](int buf, int mf, int kkj) -> bf16x8s {
        int row = wm * 128 + mf * 16 + fr;
        int e   = (kkj * 32 + fk) ^ ((row & 7) << 3);
        return *(const bf16x8s*)&Lraw[buf * 16384 + row * 64 + e];
    };
    auto rdB = [&](int buf, int nf, int kkj) -> bf16x8s {
        int row = wn * 64 + nf * 16 + fr;
        int e   = (kkj * 32 + fk) ^ ((row & 7) << 3);
        return *(const bf16x8s*)&Lraw[32768 + buf * 16384 + row * 64 + e];
    };

    const int nt = K >> 6;             // 8 (G1) or 16 (G2)

    f32x4 acc[8][4];
#pragma unroll
    for (int i = 0; i < 8; ++i)
#pragma unroll
        for (int j = 0; j < 4; ++j) acc[i][j] = f32x4{0.f, 0.f, 0.f, 0.f};

    bf16x8s aP[4], aB[4], aC[4], bX[4], bY[4];

    // ---- prologue: A(0), B(0) ; B(1) stays in flight (counted wait) ----
    stageA(0, 0); stageA(0, 1);        // 4 instrs
    stageB(0, 0);                      // 4 instrs
    if (nt > 1) {
        stageB(1, 1);                  // 4 instrs, newest
        asm volatile("s_waitcnt vmcnt(4)" ::: "memory");   // A(0),B(0) done
    } else {
        asm volatile("s_waitcnt vmcnt(0)" ::: "memory");
    }
    __builtin_amdgcn_s_barrier();
#pragma unroll
    for (int m = 0; m < 4; ++m) aP[m] = rdA(0, m, 0);
#pragma unroll
    for (int n = 0; n < 4; ++n) bX[n] = rdB(0, n, 0);

    int bc = 0;                        // B buffer of current tile
    for (int it = 0; it < nt; ++it) {
        const int cur = it & 1;
        const int bn1 = (bc == 2) ? 0 : bc + 1;    // B buf of it+1
        const int bn2 = (bn1 == 2) ? 0 : bn1 + 1;  // B buf of it+2
        const bool m1 = (it + 1 < nt), m2 = (it + 2 < nt);

        // ph0: MFMA m0-3 x k0; read A(m4-7,k0); stage A(it+1) h0
        __builtin_amdgcn_s_barrier();
#pragma unroll
        for (int m = 0; m < 4; ++m) aB[m] = rdA(cur, m + 4, 0);
        if (m1) stageA(it + 1, 0);
        __builtin_amdgcn_s_setprio(1);
#pragma unroll
        for (int m = 0; m < 4; ++m)
#pragma unroll
            for (int n = 0; n < 4; ++n) MFMA_(acc[m][n], aP[m], bX[n]);
        __builtin_amdgcn_s_setprio(0);

        // ph1: MFMA m4-7 x k0; read A(m0-3,k1)+B(k1); stage A(it+1) h1
        __builtin_amdgcn_s_barrier();
#pragma unroll
        for (int m = 0; m < 4; ++m) aC[m] = rdA(cur, m, 1);
#pragma unroll
        for (int n = 0; n < 4; ++n) bY[n] = rdB(bc, n, 1);
        if (m1) stageA(it + 1, 1);
        __builtin_amdgcn_s_setprio(1);
#pragma unroll
        for (int m = 0; m < 4; ++m)
#pragma unroll
            for (int n = 0; n < 4; ++n) MFMA_(acc[m + 4][n], aB[m], bX[n]);
        __builtin_amdgcn_s_setprio(0);

        // ph2: MFMA m0-3 x k1; read A(m4-7,k1); stage B(it+2) (newest in queue)
        __builtin_amdgcn_s_barrier();
#pragma unroll
        for (int m = 0; m < 4; ++m) aB[m] = rdA(cur, m + 4, 1);
        if (m2) stageB(bn2, it + 2);
        __builtin_amdgcn_s_setprio(1);
#pragma unroll
        for (int m = 0; m < 4; ++m)
#pragma unroll
            for (int n = 0; n < 4; ++n) MFMA_(acc[m][n], aC[m], bY[n]);
        __builtin_amdgcn_s_setprio(0);

        // ph3: counted wait for tile it+1 (leave B(it+2) in flight);
        //      read next aP/bX; MFMA m4-7 x k1
        if (m1) {
            if (m2) asm volatile("s_waitcnt vmcnt(4)" ::: "memory");
            else    asm volatile("s_waitcnt vmcnt(0)" ::: "memory");
            __builtin_amdgcn_s_barrier();
#pragma unroll
            for (int m = 0; m < 4; ++m) aP[m] = rdA(cur ^ 1, m, 0);
#pragma unroll
            for (int n = 0; n < 4; ++n) bX[n] = rdB(bn1, n, 0);
        }
        __builtin_amdgcn_s_setprio(1);
#pragma unroll
        for (int m = 0; m < 4; ++m)
#pragma unroll
            for (int n = 0; n < 4; ++n) MFMA_(acc[m + 4][n], aB[m], bY[n]);
        __builtin_amdgcn_s_setprio(0);
        bc = bn1;
    }

    __syncthreads();   // all K-loop LDS reads done before epilogue reuses LDS

    // ---------------- epilogue: row-major C [M][N] ----------------
    const int R0 = m0 + wm * 128;
    const int C0 = n0 + wn * 64;
    float bv[4];
#pragma unroll
    for (int j = 0; j < 4; ++j)
        bv[j] = bias ? bias[C0 + j * 16 + fr] : 0.f;

    if (OUT_F32) {
        float* Cb = (float*)Cout + (size_t)bat * sC;
#pragma unroll
        for (int j = 0; j < 4; ++j)
#pragma unroll
            for (int i = 0; i < 8; ++i)
#pragma unroll
                for (int e = 0; e < 4; ++e) {
                    float v = acc[i][j][e] + bv[j];
                    if (RELU) v = fmaxf(v, 0.f);
                    Cb[(size_t)(R0 + i * 16 + r4 + e) * N + C0 + j * 16 + fr] = v;
                }
    } else {
        // LDS bounce -> us8 coalesced stores
        unsigned short* sl = Lraw + wv * 8192;
#pragma unroll
        for (int i = 0; i < 8; ++i)
#pragma unroll
            for (int j = 0; j < 4; ++j)
#pragma unroll
                for (int e = 0; e < 4; ++e) {
                    float v = acc[i][j][e] + bv[j];
                    if (RELU) v = fmaxf(v, 0.f);
                    const int row = i * 16 + r4 + e;
                    const int col = j * 16 + fr;
                    sl[row * 64 + (col ^ ((row & 7) << 3))] = f2bf(v);
                }
        unsigned short* Cb = (unsigned short*)Cout + (size_t)bat * sC;
#pragma unroll
        for (int rr = 0; rr < 16; ++rr) {
            const int row = rr * 8 + (lane >> 3);
            const int k8  = lane & 7;
            us8 v = *(const us8*)&sl[row * 64 + ((k8 ^ (row & 7)) << 3)];
            *(us8*)&Cb[(size_t)(R0 + row) * N + C0 + k8 * 8] = v;
        }
    }
}

extern "C" void kernel_launch(void* const* d_in, const int* in_sizes, int n_in,
                              void* d_out, int out_size, void* d_ws, size_t ws_size,
                              hipStream_t stream) {
    constexpr int B = 32, N = 1024, F = 512;

    const float* x0f  = (const float*)d_in[0];
    const float* adjf = (const float*)d_in[1];
    const float* W1 = (const float*)d_in[2];
    const float* b1 = (const float*)d_in[3];
    const float* W2 = (const float*)d_in[4];
    const float* b2 = (const float*)d_in[5];
    const float* W3 = (const float*)d_in[6];
    const float* b3 = (const float*)d_in[7];

    unsigned short* ws   = (unsigned short*)d_ws;
    unsigned short* adjb = ws;                           // B*N*N
    unsigned short* P0   = adjb + (size_t)B * N * N;     // B*N*F  (X buffers)
    unsigned short* P1   = P0 + (size_t)B * N * F;
    unsigned short* PT   = P1 + (size_t)B * N * F;       // B*F*N  (T buffer)
    unsigned short* WT1  = PT + (size_t)B * N * F;
    unsigned short* WT2  = WT1 + (size_t)F * F;
    unsigned short* WT3  = WT2 + (size_t)F * F;

    prep<<<2048, 256, 0, stream>>>(x0f, P0, (long)B * N * F / 4,
                                   adjf, adjb, (long)B * N * N / 4,
                                   W1, W2, W3, WT1, WT2, WT3, F);

    const int grid = 256;                 // both GEMM shapes: 32 bat x 8 tiles
    const long sX = (long)N * F;
    const long sAd = (long)N * N;

    // layer 1
    gemm256<false, false><<<grid, 512, 0, stream>>>(WT1,  P0, PT, nullptr, F, N, F, 0,  sX, sX);
    gemm256<true,  false><<<grid, 512, 0, stream>>>(adjb, PT, P1, b1,      N, F, N, sAd, sX, sX);
    // layer 2
    gemm256<false, false><<<grid, 512, 0, stream>>>(WT2,  P1, PT, nullptr, F, N, F, 0,  sX, sX);
    gemm256<true,  false><<<grid, 512, 0, stream>>>(adjb, PT, P0, b2,      N, F, N, sAd, sX, sX);
    // layer 3 (fp32 out, no relu)
    gemm256<false, false><<<grid, 512, 0, stream>>>(WT3,  P0, PT, nullptr, F, N, F, 0,  sX, sX);
    gemm256<false, true ><<<grid, 512, 0, stream>>>(adjb, PT, (float*)d_out, b3, N, F, N, sAd, sX, sX);
}

// Round 10
// 255.682 us; speedup vs baseline: 2.2371x; 1.0014x over previous
//
#include <hip/hip_runtime.h>
#include <hip/hip_bf16.h>

// GCN: 3 x [ relu(A @ (X @ W) + b) ]  (no relu layer 3), fp32 I/O, bf16 MFMA.
// All-row-major chain:
//   G1: T  = W^T @ X^T : gemm(A=WT [F][F], BT=X [N][F]) -> T [F][N]
//   G2: X' = adj @ T^T : gemm(A=adj [N][N], BT=T [F][N]) -> X' [N][F] (+b, relu)
// GEMM core = R8 (proven -17%): 160KB LDS, A dbuf + B TRIPLE-buf, B staged 2
// tiles ahead, counted vmcnt(4), read-ahead 4-phase pipeline, XOR-swizzled
// LDS, setprio, XCD swizzle, LDS-bounced us8 epilogue.
// R9: prep rewritten for MLP — compile-time trip counts, float4-pair loads,
// us8 16B stores, 4x unroll => 8 outstanding loads/wave (was ~1; 2.3 TB/s).

typedef __attribute__((ext_vector_type(8))) short bf16x8s;
typedef __attribute__((ext_vector_type(4))) float f32x4;
typedef __attribute__((ext_vector_type(4))) unsigned short us4;
typedef __attribute__((ext_vector_type(8))) unsigned short us8;

__device__ __forceinline__ unsigned short f2bf(float f) {
    unsigned u = __builtin_bit_cast(unsigned, f);
    u += 0x7fffu + ((u >> 16) & 1u);          // RNE
    return (unsigned short)(u >> 16);
}

__device__ __forceinline__ us8 pack8(float4 a, float4 b) {
    us8 o;
    o[0] = f2bf(a.x); o[1] = f2bf(a.y); o[2] = f2bf(a.z); o[3] = f2bf(a.w);
    o[4] = f2bf(b.x); o[5] = f2bf(b.y); o[6] = f2bf(b.z); o[7] = f2bf(b.w);
    return o;
}

__device__ __forceinline__ void async16(const unsigned short* g, unsigned short* l) {
    __builtin_amdgcn_global_load_lds(
        (const __attribute__((address_space(1))) unsigned int*)g,
        (__attribute__((address_space(3))) unsigned int*)l, 16, 0, 0);
}

#define MFMA_(d, va, vb) d = __builtin_amdgcn_mfma_f32_16x16x32_bf16(va, vb, d, 0, 0, 0)

// -------- prep: adj + x0 f32->bf16 (MLP-unrolled) + three W transposes --------
// Launch: exactly 2048 blocks x 256 threads (S = 524288 threads total).
__global__ void prep(const float* __restrict__ x0, unsigned short* __restrict__ P0,
                     const float* __restrict__ adjf, unsigned short* __restrict__ adjb,
                     const float* __restrict__ W1, const float* __restrict__ W2,
                     const float* __restrict__ W3, unsigned short* __restrict__ WT1,
                     unsigned short* __restrict__ WT2, unsigned short* __restrict__ WT3) {
    constexpr long S  = 2048L * 256;          // total threads
    constexpr long PA = 33554432L / 8;        // adj us8-outputs: 4,194,304 = 8*S
    constexpr long PX = 16777216L / 8;        // x0  us8-outputs: 2,097,152 = 4*S
    constexpr int  F  = 512;
    const long tid = (long)blockIdx.x * 256 + threadIdx.x;

    {   // adj: 8 pair-iters = 2 groups of 4 (8 loads in flight per group)
        const float4* src = (const float4*)adjf;
        us8* dst = (us8*)adjb;
#pragma unroll
        for (int j = 0; j < 2; ++j) {
            long p0 = tid + (j * 4 + 0) * S;
            long p1 = tid + (j * 4 + 1) * S;
            long p2 = tid + (j * 4 + 2) * S;
            long p3 = tid + (j * 4 + 3) * S;
            float4 a0 = src[2*p0], b0 = src[2*p0+1];
            float4 a1 = src[2*p1], b1 = src[2*p1+1];
            float4 a2 = src[2*p2], b2 = src[2*p2+1];
            float4 a3 = src[2*p3], b3 = src[2*p3+1];
            dst[p0] = pack8(a0, b0);
            dst[p1] = pack8(a1, b1);
            dst[p2] = pack8(a2, b2);
            dst[p3] = pack8(a3, b3);
        }
        (void)PA;
    }
    {   // x0: 4 pair-iters = 1 group of 4
        const float4* src = (const float4*)x0;
        us8* dst = (us8*)P0;
        long p0 = tid + 0 * S;
        long p1 = tid + 1 * S;
        long p2 = tid + 2 * S;
        long p3 = tid + 3 * S;
        float4 a0 = src[2*p0], b0 = src[2*p0+1];
        float4 a1 = src[2*p1], b1 = src[2*p1+1];
        float4 a2 = src[2*p2], b2 = src[2*p2+1];
        float4 a3 = src[2*p3], b3 = src[2*p3+1];
        dst[p0] = pack8(a0, b0);
        dst[p1] = pack8(a1, b1);
        dst[p2] = pack8(a2, b2);
        dst[p3] = pack8(a3, b3);
        (void)PX;
    }
    {   // W transposes: 3*F*F = 786432 elems over 524288 threads
        const long FF = (long)F * F;
        for (long k = tid; k < 3 * FF; k += S) {
            int w = (int)(k / FF);
            long idx = k % FF;                 // output-linear: coalesced writes
            int r = (int)(idx % F);
            int c = (int)(idx / F);
            const float* W = (w == 0) ? W1 : (w == 1) ? W2 : W3;
            unsigned short* WT = (w == 0) ? WT1 : (w == 1) ? WT2 : WT3;
            WT[idx] = f2bf(W[(size_t)r * F + c]);
        }
    }
}

// ---------------- batched GEMM C = A @ B,  B given transposed ----------------
// A : bf16 [bat][M][K] (sA==0 -> shared); BT : bf16 [bat][N][K]
// Out row-major [bat][M][N]; bias by col (nullptr ok); optional relu/f32.
template<bool RELU, bool OUT_F32>
__global__ __launch_bounds__(512, 2)
void gemm256(const unsigned short* __restrict__ A,
             const unsigned short* __restrict__ BT,
             void* __restrict__ Cout,
             const float* __restrict__ bias,
             int M, int N, int K,
             long sA, long sBT, long sC)
{
    // 160 KiB LDS: A dbuf [0, 32K elems) ; B tripbuf [32K, 80K elems)
    __shared__ unsigned short Lraw[81920];

    const int t    = threadIdx.x;
    const int lane = t & 63;
    const int wv   = t >> 6;
    const int wm   = wv >> 2;          // 0..1  -> 128-row half
    const int wn   = wv & 3;           // 0..3  -> 64-col strip
    const int fr   = lane & 15;
    const int fk   = (lane >> 4) * 8;
    const int r4   = (lane >> 4) * 4;

    const int tilesN = N >> 8;
    const int bpb    = (M >> 8) * tilesN;
    const int cpx = gridDim.x >> 3;    // grid divisible by 8 -> bijective
    const int lb  = (blockIdx.x & 7) * cpx + (blockIdx.x >> 3);
    const int bat = lb / bpb;
    const int tt  = lb % bpb;
    const int m0  = (tt / tilesN) << 8;
    const int n0  = (tt % tilesN) << 8;

    const unsigned short* Ab = A  + (size_t)bat * sA  + (size_t)m0 * K;
    const unsigned short* Bb = BT + (size_t)bat * sBT + (size_t)n0 * K;

    // staging: chunk c = r*512+t -> LDS elems [c*8, c*8+8) of a 128-row half
    int srow[2], scol[2], lo[2];
#pragma unroll
    for (int r = 0; r < 2; ++r) {
        int c   = r * 512 + t;
        srow[r] = c >> 3;
        scol[r] = ((c & 7) * 8) ^ ((srow[r] & 7) << 3);
        lo[r]   = c * 8;
    }

    auto stageA = [&](int kt, int h) {              // 2 instrs
        unsigned short* base = Lraw + (kt & 1) * 16384;
#pragma unroll
        for (int r = 0; r < 2; ++r)
            async16(Ab + (size_t)(h * 128 + srow[r]) * K + kt * 64 + scol[r],
                    base + h * 8192 + lo[r]);
    };
    auto stageB = [&](int buf, int kt) {            // both halves, 4 instrs
        unsigned short* base = Lraw + 32768 + buf * 16384;
#pragma unroll
        for (int h = 0; h < 2; ++h)
#pragma unroll
            for (int r = 0; r < 2; ++r)
                async16(Bb + (size_t)(h * 128 + srow[r]) * K + kt * 64 + scol[r],
                        base + h * 8192 + lo[r]);
    };
    auto rdA = [&](int buf, int mf, int kkj) -> bf16x8s {
        int row = wm * 128 + mf * 16 + fr;
        int e   = (kkj * 32 + fk) ^ ((row & 7) << 3);
        return *(const bf16x8s*)&Lraw[buf * 16384 + row * 64 + e];
    };
    auto rdB = [&](int buf, int nf, int kkj) -> bf16x8s {
        int row = wn * 64 + nf * 16 + fr;
        int e   = (kkj * 32 + fk) ^ ((row & 7) << 3);
        return *(const bf16x8s*)&Lraw[32768 + buf * 16384 + row * 64 + e];
    };

    const int nt = K >> 6;             // 8 (G1) or 16 (G2)

    f32x4 acc[8][4];
#pragma unroll
    for (int i = 0; i < 8; ++i)
#pragma unroll
        for (int j = 0; j < 4; ++j) acc[i][j] = f32x4{0.f, 0.f, 0.f, 0.f};

    bf16x8s aP[4], aB[4], aC[4], bX[4], bY[4];

    // ---- prologue: A(0), B(0) ; B(1) stays in flight (counted wait) ----
    stageA(0, 0); stageA(0, 1);        // 4 instrs
    stageB(0, 0);                      // 4 instrs
    if (nt > 1) {
        stageB(1, 1);                  // 4 instrs, newest
        asm volatile("s_waitcnt vmcnt(4)" ::: "memory");   // A(0),B(0) done
    } else {
        asm volatile("s_waitcnt vmcnt(0)" ::: "memory");
    }
    __builtin_amdgcn_s_barrier();
#pragma unroll
    for (int m = 0; m < 4; ++m) aP[m] = rdA(0, m, 0);
#pragma unroll
    for (int n = 0; n < 4; ++n) bX[n] = rdB(0, n, 0);

    int bc = 0;                        // B buffer of current tile
    for (int it = 0; it < nt; ++it) {
        const int cur = it & 1;
        const int bn1 = (bc == 2) ? 0 : bc + 1;    // B buf of it+1
        const int bn2 = (bn1 == 2) ? 0 : bn1 + 1;  // B buf of it+2
        const bool m1 = (it + 1 < nt), m2 = (it + 2 < nt);

        // ph0: MFMA m0-3 x k0; read A(m4-7,k0); stage A(it+1) h0
        __builtin_amdgcn_s_barrier();
#pragma unroll
        for (int m = 0; m < 4; ++m) aB[m] = rdA(cur, m + 4, 0);
        if (m1) stageA(it + 1, 0);
        __builtin_amdgcn_s_setprio(1);
#pragma unroll
        for (int m = 0; m < 4; ++m)
#pragma unroll
            for (int n = 0; n < 4; ++n) MFMA_(acc[m][n], aP[m], bX[n]);
        __builtin_amdgcn_s_setprio(0);

        // ph1: MFMA m4-7 x k0; read A(m0-3,k1)+B(k1); stage A(it+1) h1
        __builtin_amdgcn_s_barrier();
#pragma unroll
        for (int m = 0; m < 4; ++m) aC[m] = rdA(cur, m, 1);
#pragma unroll
        for (int n = 0; n < 4; ++n) bY[n] = rdB(bc, n, 1);
        if (m1) stageA(it + 1, 1);
        __builtin_amdgcn_s_setprio(1);
#pragma unroll
        for (int m = 0; m < 4; ++m)
#pragma unroll
            for (int n = 0; n < 4; ++n) MFMA_(acc[m + 4][n], aB[m], bX[n]);
        __builtin_amdgcn_s_setprio(0);

        // ph2: MFMA m0-3 x k1; read A(m4-7,k1); stage B(it+2) (newest in queue)
        __builtin_amdgcn_s_barrier();
#pragma unroll
        for (int m = 0; m < 4; ++m) aB[m] = rdA(cur, m + 4, 1);
        if (m2) stageB(bn2, it + 2);
        __builtin_amdgcn_s_setprio(1);
#pragma unroll
        for (int m = 0; m < 4; ++m)
#pragma unroll
            for (int n = 0; n < 4; ++n) MFMA_(acc[m][n], aC[m], bY[n]);
        __builtin_amdgcn_s_setprio(0);

        // ph3: counted wait for tile it+1 (leave B(it+2) in flight);
        //      read next aP/bX; MFMA m4-7 x k1
        if (m1) {
            if (m2) asm volatile("s_waitcnt vmcnt(4)" ::: "memory");
            else    asm volatile("s_waitcnt vmcnt(0)" ::: "memory");
            __builtin_amdgcn_s_barrier();
#pragma unroll
            for (int m = 0; m < 4; ++m) aP[m] = rdA(cur ^ 1, m, 0);
#pragma unroll
            for (int n = 0; n < 4; ++n) bX[n] = rdB(bn1, n, 0);
        }
        __builtin_amdgcn_s_setprio(1);
#pragma unroll
        for (int m = 0; m < 4; ++m)
#pragma unroll
            for (int n = 0; n < 4; ++n) MFMA_(acc[m + 4][n], aB[m], bY[n]);
        __builtin_amdgcn_s_setprio(0);
        bc = bn1;
    }

    __syncthreads();   // all K-loop LDS reads done before epilogue reuses LDS

    // ---------------- epilogue: row-major C [M][N] ----------------
    const int R0 = m0 + wm * 128;
    const int C0 = n0 + wn * 64;
    float bv[4];
#pragma unroll
    for (int j = 0; j < 4; ++j)
        bv[j] = bias ? bias[C0 + j * 16 + fr] : 0.f;

    if (OUT_F32) {
        float* Cb = (float*)Cout + (size_t)bat * sC;
#pragma unroll
        for (int j = 0; j < 4; ++j)
#pragma unroll
            for (int i = 0; i < 8; ++i)
#pragma unroll
                for (int e = 0; e < 4; ++e) {
                    float v = acc[i][j][e] + bv[j];
                    if (RELU) v = fmaxf(v, 0.f);
                    Cb[(size_t)(R0 + i * 16 + r4 + e) * N + C0 + j * 16 + fr] = v;
                }
    } else {
        // LDS bounce -> us8 coalesced stores
        unsigned short* sl = Lraw + wv * 8192;
#pragma unroll
        for (int i = 0; i < 8; ++i)
#pragma unroll
            for (int j = 0; j < 4; ++j)
#pragma unroll
                for (int e = 0; e < 4; ++e) {
                    float v = acc[i][j][e] + bv[j];
                    if (RELU) v = fmaxf(v, 0.f);
                    const int row = i * 16 + r4 + e;
                    const int col = j * 16 + fr;
                    sl[row * 64 + (col ^ ((row & 7) << 3))] = f2bf(v);
                }
        unsigned short* Cb = (unsigned short*)Cout + (size_t)bat * sC;
#pragma unroll
        for (int rr = 0; rr < 16; ++rr) {
            const int row = rr * 8 + (lane >> 3);
            const int k8  = lane & 7;
            us8 v = *(const us8*)&sl[row * 64 + ((k8 ^ (row & 7)) << 3)];
            *(us8*)&Cb[(size_t)(R0 + row) * N + C0 + k8 * 8] = v;
        }
    }
}

extern "C" void kernel_launch(void* const* d_in, const int* in_sizes, int n_in,
                              void* d_out, int out_size, void* d_ws, size_t ws_size,
                              hipStream_t stream) {
    constexpr int B = 32, N = 1024, F = 512;

    const float* x0f  = (const float*)d_in[0];
    const float* adjf = (const float*)d_in[1];
    const float* W1 = (const float*)d_in[2];
    const float* b1 = (const float*)d_in[3];
    const float* W2 = (const float*)d_in[4];
    const float* b2 = (const float*)d_in[5];
    const float* W3 = (const float*)d_in[6];
    const float* b3 = (const float*)d_in[7];

    unsigned short* ws   = (unsigned short*)d_ws;
    unsigned short* adjb = ws;                           // B*N*N
    unsigned short* P0   = adjb + (size_t)B * N * N;     // B*N*F  (X buffers)
    unsigned short* P1   = P0 + (size_t)B * N * F;
    unsigned short* PT   = P1 + (size_t)B * N * F;       // B*F*N  (T buffer)
    unsigned short* WT1  = PT + (size_t)B * N * F;
    unsigned short* WT2  = WT1 + (size_t)F * F;
    unsigned short* WT3  = WT2 + (size_t)F * F;

    prep<<<2048, 256, 0, stream>>>(x0f, P0, adjf, adjb,
                                   W1, W2, W3, WT1, WT2, WT3);

    const int grid = 256;                 // both GEMM shapes: 32 bat x 8 tiles
    const long sX = (long)N * F;
    const long sAd = (long)N * N;

    // layer 1
    gemm256<false, false><<<grid, 512, 0, stream>>>(WT1,  P0, PT, nullptr, F, N, F, 0,  sX, sX);
    gemm256<true,  false><<<grid, 512, 0, stream>>>(adjb, PT, P1, b1,      N, F, N, sAd, sX, sX);
    // layer 2
    gemm256<false, false><<<grid, 512, 0, stream>>>(WT2,  P1, PT, nullptr, F, N, F, 0,  sX, sX);
    gemm256<true,  false><<<grid, 512, 0, stream>>>(adjb, PT, P0, b2,      N, F, N, sAd, sX, sX);
    // layer 3 (fp32 out, no relu)
    gemm256<false, false><<<grid, 512, 0, stream>>>(WT3,  P0, PT, nullptr, F, N, F, 0,  sX, sX);
    gemm256<false, true ><<<grid, 512, 0, stream>>>(adjb, PT, (float*)d_out, b3, N, F, N, sAd, sX, sX);
}

// Round 11
// 239.028 us; speedup vs baseline: 2.3930x; 1.0697x over previous
//
#include <hip/hip_runtime.h>
#include <hip/hip_bf16.h>

// GCN: 3 x [ relu(A @ (X @ W) + b) ]  (no relu layer 3), fp32 I/O, bf16 MFMA.
// R10: NO separate conversion pass. Layer-1 GEMMs consume f32 inputs directly
// via reg-staging (global f32 -> reg -> pack bf16 -> ds_write), hiding the
// convert under MFMA. G2_1 additionally writes packed adj bf16 back to adjb
// (n0==0 blocks) for layers 2/3. prep = 3MB W-transpose only.
//   G1: T  = W^T @ X^T : gemm(A=WT [F][F], BT=X [N][F]) -> T [F][N]
//   G2: X' = adj @ T^T : gemm(A=adj [N][N], BT=T [F][N]) -> X' [N][F] (+b,relu)
// Unfused GEMMs: R8 core verbatim (160KB LDS, A dbuf + B triple-buf, counted
// vmcnt(4)). Fused kernels: 128KB LDS, both operands double-buffered.

typedef __attribute__((ext_vector_type(8))) short bf16x8s;
typedef __attribute__((ext_vector_type(4))) float f32x4;
typedef __attribute__((ext_vector_type(4))) unsigned short us4;
typedef __attribute__((ext_vector_type(8))) unsigned short us8;

__device__ __forceinline__ unsigned short f2bf(float f) {
    unsigned u = __builtin_bit_cast(unsigned, f);
    u += 0x7fffu + ((u >> 16) & 1u);          // RNE
    return (unsigned short)(u >> 16);
}

__device__ __forceinline__ us8 pack8(float4 a, float4 b) {
    us8 o;
    o[0] = f2bf(a.x); o[1] = f2bf(a.y); o[2] = f2bf(a.z); o[3] = f2bf(a.w);
    o[4] = f2bf(b.x); o[5] = f2bf(b.y); o[6] = f2bf(b.z); o[7] = f2bf(b.w);
    return o;
}

__device__ __forceinline__ void async16(const unsigned short* g, unsigned short* l) {
    __builtin_amdgcn_global_load_lds(
        (const __attribute__((address_space(1))) unsigned int*)g,
        (__attribute__((address_space(3))) unsigned int*)l, 16, 0, 0);
}

#define MFMA_(d, va, vb) d = __builtin_amdgcn_mfma_f32_16x16x32_bf16(va, vb, d, 0, 0, 0)

// -------- prep: three W transposes only (3 MB) --------
__global__ void prep(const float* __restrict__ W1, const float* __restrict__ W2,
                     const float* __restrict__ W3, unsigned short* __restrict__ WT1,
                     unsigned short* __restrict__ WT2, unsigned short* __restrict__ WT3) {
    constexpr int F = 512;
    const long FF = (long)F * F;
    const long S = (long)gridDim.x * 256;
    for (long k = (long)blockIdx.x * 256 + threadIdx.x; k < 3 * FF; k += S) {
        int w = (int)(k / FF);
        long idx = k % FF;
        int r = (int)(idx % F);
        int c = (int)(idx / F);
        const float* W = (w == 0) ? W1 : (w == 1) ? W2 : W3;
        unsigned short* WT = (w == 0) ? WT1 : (w == 1) ? WT2 : WT3;
        WT[idx] = f2bf(W[(size_t)r * F + c]);
    }
}

// ================= fused G1 layer-1: PT = WT1 @ X0^T (X0 = f32) =============
__global__ __launch_bounds__(512, 2)
void gemm_g1f(const unsigned short* __restrict__ WT,   // [512][512] bf16
              const float* __restrict__ X0,            // [32][1024][512] f32
              unsigned short* __restrict__ PT)         // [32][512][1024] bf16
{
    constexpr int K = 512, NN = 1024;
    constexpr int nt = K >> 6;                          // 8
    __shared__ unsigned short Lraw[65536];              // A dbuf 64KB | B dbuf 64KB

    const int t = threadIdx.x, lane = t & 63, wv = t >> 6;
    const int wm = wv >> 2, wn = wv & 3;
    const int fr = lane & 15, fk = (lane >> 4) * 8, r4 = (lane >> 4) * 4;
    const int lb = ((int)blockIdx.x & 7) * 32 + ((int)blockIdx.x >> 3);
    const int bat = lb >> 3, tt = lb & 7;
    const int m0 = (tt >> 2) << 8, n0 = (tt & 3) << 8;  // 2 M-tiles x 4 N-tiles

    const unsigned short* Ab = WT + (size_t)m0 * K;
    const float* Bb = X0 + (size_t)bat * NN * K + (size_t)n0 * K;

    int srow[2], scol[2], lo[2];
#pragma unroll
    for (int r = 0; r < 2; ++r) {
        int c   = r * 512 + t;
        srow[r] = c >> 3;
        scol[r] = ((c & 7) * 8) ^ ((srow[r] & 7) << 3);
        lo[r]   = c * 8;
    }

    auto stageA = [&](int kt, int h) {
        unsigned short* base = Lraw + (kt & 1) * 16384;
#pragma unroll
        for (int r = 0; r < 2; ++r)
            async16(Ab + (size_t)(h * 128 + srow[r]) * K + kt * 64 + scol[r],
                    base + h * 8192 + lo[r]);
    };
    auto rdA = [&](int buf, int mf, int kkj) -> bf16x8s {
        int row = wm * 128 + mf * 16 + fr;
        int e   = (kkj * 32 + fk) ^ ((row & 7) << 3);
        return *(const bf16x8s*)&Lraw[buf * 16384 + row * 64 + e];
    };
    auto rdB = [&](int buf, int nf, int kkj) -> bf16x8s {
        int row = wn * 64 + nf * 16 + fr;
        int e   = (kkj * 32 + fk) ^ ((row & 7) << 3);
        return *(const bf16x8s*)&Lraw[32768 + buf * 16384 + row * 64 + e];
    };

    float4 fa[4], fb[4];
    auto loadB = [&](int kt) {
#pragma unroll
        for (int h = 0; h < 2; ++h)
#pragma unroll
            for (int r = 0; r < 2; ++r) {
                const float* p = Bb + (size_t)(h * 128 + srow[r]) * K + kt * 64 + scol[r];
                fa[h * 2 + r] = *(const float4*)p;
                fb[h * 2 + r] = *(const float4*)(p + 4);
            }
    };
    auto writeB = [&](int buf) {
#pragma unroll
        for (int h = 0; h < 2; ++h)
#pragma unroll
            for (int r = 0; r < 2; ++r)
                *(us8*)&Lraw[32768 + buf * 16384 + h * 8192 + lo[r]] =
                    pack8(fa[h * 2 + r], fb[h * 2 + r]);
    };

    f32x4 acc[8][4];
#pragma unroll
    for (int i = 0; i < 8; ++i)
#pragma unroll
        for (int j = 0; j < 4; ++j) acc[i][j] = f32x4{0.f, 0.f, 0.f, 0.f};
    bf16x8s aP[4], aB[4], aC[4], bX[4], bY[4];

    // prologue: B(0) f32->LDS, A(0) async, B(1) f32 in regs
    loadB(0);
    stageA(0, 0); stageA(0, 1);
    writeB(0);
    loadB(1);
    __syncthreads();
#pragma unroll
    for (int m = 0; m < 4; ++m) aP[m] = rdA(0, m, 0);
#pragma unroll
    for (int n = 0; n < 4; ++n) bX[n] = rdB(0, n, 0);

    for (int it = 0; it < nt; ++it) {
        const int cur = it & 1, nxt = cur ^ 1;
        const bool m1 = it + 1 < nt, m2 = it + 2 < nt;

        __builtin_amdgcn_s_barrier();                       // ph0
#pragma unroll
        for (int m = 0; m < 4; ++m) aB[m] = rdA(cur, m + 4, 0);
        if (m1) stageA(it + 1, 0);
        __builtin_amdgcn_s_setprio(1);
#pragma unroll
        for (int m = 0; m < 4; ++m)
#pragma unroll
            for (int n = 0; n < 4; ++n) MFMA_(acc[m][n], aP[m], bX[n]);
        __builtin_amdgcn_s_setprio(0);

        __builtin_amdgcn_s_barrier();                       // ph1
#pragma unroll
        for (int m = 0; m < 4; ++m) aC[m] = rdA(cur, m, 1);
#pragma unroll
        for (int n = 0; n < 4; ++n) bY[n] = rdB(cur, n, 1);
        if (m1) stageA(it + 1, 1);
        __builtin_amdgcn_s_setprio(1);
#pragma unroll
        for (int m = 0; m < 4; ++m)
#pragma unroll
            for (int n = 0; n < 4; ++n) MFMA_(acc[m + 4][n], aB[m], bX[n]);
        __builtin_amdgcn_s_setprio(0);

        __builtin_amdgcn_s_barrier();                       // ph2
#pragma unroll
        for (int m = 0; m < 4; ++m) aB[m] = rdA(cur, m + 4, 1);
        if (m1) writeB(nxt);                                // cvt + ds_write B(it+1)
        __builtin_amdgcn_s_setprio(1);
#pragma unroll
        for (int m = 0; m < 4; ++m)
#pragma unroll
            for (int n = 0; n < 4; ++n) MFMA_(acc[m][n], aC[m], bY[n]);
        __builtin_amdgcn_s_setprio(0);

        if (m1) {                                           // ph3
            asm volatile("s_waitcnt vmcnt(0) lgkmcnt(0)" ::: "memory");
            __builtin_amdgcn_s_barrier();
#pragma unroll
            for (int m = 0; m < 4; ++m) aP[m] = rdA(nxt, m, 0);
#pragma unroll
            for (int n = 0; n < 4; ++n) bX[n] = rdB(nxt, n, 0);
            if (m2) loadB(it + 2);
        }
        __builtin_amdgcn_s_setprio(1);
#pragma unroll
        for (int m = 0; m < 4; ++m)
#pragma unroll
            for (int n = 0; n < 4; ++n) MFMA_(acc[m + 4][n], aB[m], bY[n]);
        __builtin_amdgcn_s_setprio(0);
    }

    __syncthreads();
    // epilogue: LDS bounce -> us8 coalesced stores, PT row-major [512][1024]
    const int R0 = m0 + wm * 128;
    const int C0 = n0 + wn * 64;
    unsigned short* sl = Lraw + wv * 8192;
#pragma unroll
    for (int i = 0; i < 8; ++i)
#pragma unroll
        for (int j = 0; j < 4; ++j)
#pragma unroll
            for (int e = 0; e < 4; ++e) {
                const int row = i * 16 + r4 + e;
                const int col = j * 16 + fr;
                sl[row * 64 + (col ^ ((row & 7) << 3))] = f2bf(acc[i][j][e]);
            }
    unsigned short* Cb = PT + (size_t)bat * 512 * 1024;
#pragma unroll
    for (int rr = 0; rr < 16; ++rr) {
        const int row = rr * 8 + (lane >> 3);
        const int k8  = lane & 7;
        us8 v = *(const us8*)&sl[row * 64 + ((k8 ^ (row & 7)) << 3)];
        *(us8*)&Cb[(size_t)(R0 + row) * NN + C0 + k8 * 8] = v;
    }
}

// ====== fused G2 layer-1: P1 = relu(adj @ PT^T + b1), adj f32 + writeback ===
__global__ __launch_bounds__(512, 2)
void gemm_g2f(const float* __restrict__ ADJ,            // [32][1024][1024] f32
              unsigned short* __restrict__ adjb,        // bf16 out (plain layout)
              const unsigned short* __restrict__ PT,    // [32][512][1024] bf16
              unsigned short* __restrict__ P1,          // [32][1024][512] bf16
              const float* __restrict__ bias)
{
    constexpr int K = 1024, NN = 512;
    constexpr int nt = K >> 6;                          // 16
    __shared__ unsigned short Lraw[65536];              // A dbuf | B dbuf

    const int t = threadIdx.x, lane = t & 63, wv = t >> 6;
    const int wm = wv >> 2, wn = wv & 3;
    const int fr = lane & 15, fk = (lane >> 4) * 8, r4 = (lane >> 4) * 4;
    const int lb = ((int)blockIdx.x & 7) * 32 + ((int)blockIdx.x >> 3);
    const int bat = lb >> 3, tt = lb & 7;
    const int m0 = (tt >> 1) << 8, n0 = (tt & 1) << 8;  // 4 M-tiles x 2 N-tiles
    const bool wb = (n0 == 0);

    const float* Afb = ADJ + (size_t)bat * K * K + (size_t)m0 * K;
    unsigned short* Awb = adjb + (size_t)bat * K * K + (size_t)m0 * K;
    const unsigned short* Bb = PT + (size_t)bat * NN * K + (size_t)n0 * K;

    int srow[2], scol[2], lo[2];
#pragma unroll
    for (int r = 0; r < 2; ++r) {
        int c   = r * 512 + t;
        srow[r] = c >> 3;
        scol[r] = ((c & 7) * 8) ^ ((srow[r] & 7) << 3);
        lo[r]   = c * 8;
    }

    auto stageB = [&](int kt, int h) {
        unsigned short* base = Lraw + 32768 + (kt & 1) * 16384;
#pragma unroll
        for (int r = 0; r < 2; ++r)
            async16(Bb + (size_t)(h * 128 + srow[r]) * K + kt * 64 + scol[r],
                    base + h * 8192 + lo[r]);
    };
    auto rdA = [&](int buf, int mf, int kkj) -> bf16x8s {
        int row = wm * 128 + mf * 16 + fr;
        int e   = (kkj * 32 + fk) ^ ((row & 7) << 3);
        return *(const bf16x8s*)&Lraw[buf * 16384 + row * 64 + e];
    };
    auto rdB = [&](int buf, int nf, int kkj) -> bf16x8s {
        int row = wn * 64 + nf * 16 + fr;
        int e   = (kkj * 32 + fk) ^ ((row & 7) << 3);
        return *(const bf16x8s*)&Lraw[32768 + buf * 16384 + row * 64 + e];
    };

    float4 fa[4], fb[4];
    auto loadA = [&](int kt) {
#pragma unroll
        for (int h = 0; h < 2; ++h)
#pragma unroll
            for (int r = 0; r < 2; ++r) {
                const float* p = Afb + (size_t)(h * 128 + srow[r]) * K + kt * 64 + scol[r];
                fa[h * 2 + r] = *(const float4*)p;
                fb[h * 2 + r] = *(const float4*)(p + 4);
            }
    };
    auto flushA = [&](int buf, int kt) {                // cvt + ds_write + writeback
#pragma unroll
        for (int h = 0; h < 2; ++h)
#pragma unroll
            for (int r = 0; r < 2; ++r) {
                us8 v = pack8(fa[h * 2 + r], fb[h * 2 + r]);
                *(us8*)&Lraw[buf * 16384 + h * 8192 + lo[r]] = v;
                if (wb)
                    *(us8*)&Awb[(size_t)(h * 128 + srow[r]) * K + kt * 64 + scol[r]] = v;
            }
    };

    f32x4 acc[8][4];
#pragma unroll
    for (int i = 0; i < 8; ++i)
#pragma unroll
        for (int j = 0; j < 4; ++j) acc[i][j] = f32x4{0.f, 0.f, 0.f, 0.f};
    bf16x8s aP[4], aB[4], aC[4], bX[4], bY[4];

    // prologue
    loadA(0);
    stageB(0, 0); stageB(0, 1);
    flushA(0, 0);
    loadA(1);
    __syncthreads();
#pragma unroll
    for (int m = 0; m < 4; ++m) aP[m] = rdA(0, m, 0);
#pragma unroll
    for (int n = 0; n < 4; ++n) bX[n] = rdB(0, n, 0);

    for (int it = 0; it < nt; ++it) {
        const int cur = it & 1, nxt = cur ^ 1;
        const bool m1 = it + 1 < nt, m2 = it + 2 < nt;

        __builtin_amdgcn_s_barrier();                       // ph0
#pragma unroll
        for (int m = 0; m < 4; ++m) aB[m] = rdA(cur, m + 4, 0);
        if (m1) stageB(it + 1, 0);
        __builtin_amdgcn_s_setprio(1);
#pragma unroll
        for (int m = 0; m < 4; ++m)
#pragma unroll
            for (int n = 0; n < 4; ++n) MFMA_(acc[m][n], aP[m], bX[n]);
        __builtin_amdgcn_s_setprio(0);

        __builtin_amdgcn_s_barrier();                       // ph1
#pragma unroll
        for (int m = 0; m < 4; ++m) aC[m] = rdA(cur, m, 1);
#pragma unroll
        for (int n = 0; n < 4; ++n) bY[n] = rdB(cur, n, 1);
        if (m1) stageB(it + 1, 1);
        __builtin_amdgcn_s_setprio(1);
#pragma unroll
        for (int m = 0; m < 4; ++m)
#pragma unroll
            for (int n = 0; n < 4; ++n) MFMA_(acc[m + 4][n], aB[m], bX[n]);
        __builtin_amdgcn_s_setprio(0);

        __builtin_amdgcn_s_barrier();                       // ph2
#pragma unroll
        for (int m = 0; m < 4; ++m) aB[m] = rdA(cur, m + 4, 1);
        if (m1) flushA(nxt, it + 1);
        __builtin_amdgcn_s_setprio(1);
#pragma unroll
        for (int m = 0; m < 4; ++m)
#pragma unroll
            for (int n = 0; n < 4; ++n) MFMA_(acc[m][n], aC[m], bY[n]);
        __builtin_amdgcn_s_setprio(0);

        if (m1) {                                           // ph3
            asm volatile("s_waitcnt vmcnt(0) lgkmcnt(0)" ::: "memory");
            __builtin_amdgcn_s_barrier();
#pragma unroll
            for (int m = 0; m < 4; ++m) aP[m] = rdA(nxt, m, 0);
#pragma unroll
            for (int n = 0; n < 4; ++n) bX[n] = rdB(nxt, n, 0);
            if (m2) loadA(it + 2);
        }
        __builtin_amdgcn_s_setprio(1);
#pragma unroll
        for (int m = 0; m < 4; ++m)
#pragma unroll
            for (int n = 0; n < 4; ++n) MFMA_(acc[m + 4][n], aB[m], bY[n]);
        __builtin_amdgcn_s_setprio(0);
    }

    __syncthreads();
    // epilogue: bias + relu, LDS bounce, P1 row-major [1024][512]
    const int R0 = m0 + wm * 128;
    const int C0 = n0 + wn * 64;
    float bv[4];
#pragma unroll
    for (int j = 0; j < 4; ++j) bv[j] = bias[C0 + j * 16 + fr];
    unsigned short* sl = Lraw + wv * 8192;
#pragma unroll
    for (int i = 0; i < 8; ++i)
#pragma unroll
        for (int j = 0; j < 4; ++j)
#pragma unroll
            for (int e = 0; e < 4; ++e) {
                const int row = i * 16 + r4 + e;
                const int col = j * 16 + fr;
                sl[row * 64 + (col ^ ((row & 7) << 3))] =
                    f2bf(fmaxf(acc[i][j][e] + bv[j], 0.f));
            }
    unsigned short* Cb = P1 + (size_t)bat * 1024 * 512;
#pragma unroll
    for (int rr = 0; rr < 16; ++rr) {
        const int row = rr * 8 + (lane >> 3);
        const int k8  = lane & 7;
        us8 v = *(const us8*)&sl[row * 64 + ((k8 ^ (row & 7)) << 3)];
        *(us8*)&Cb[(size_t)(R0 + row) * NN + C0 + k8 * 8] = v;
    }
}

// ================= R8 core (unchanged) for the 4 bf16 GEMMs =================
template<bool RELU, bool OUT_F32>
__global__ __launch_bounds__(512, 2)
void gemm256(const unsigned short* __restrict__ A,
             const unsigned short* __restrict__ BT,
             void* __restrict__ Cout,
             const float* __restrict__ bias,
             int M, int N, int K,
             long sA, long sBT, long sC)
{
    __shared__ unsigned short Lraw[81920];

    const int t    = threadIdx.x;
    const int lane = t & 63;
    const int wv   = t >> 6;
    const int wm   = wv >> 2;
    const int wn   = wv & 3;
    const int fr   = lane & 15;
    const int fk   = (lane >> 4) * 8;
    const int r4   = (lane >> 4) * 4;

    const int tilesN = N >> 8;
    const int bpb    = (M >> 8) * tilesN;
    const int cpx = gridDim.x >> 3;
    const int lb  = (blockIdx.x & 7) * cpx + (blockIdx.x >> 3);
    const int bat = lb / bpb;
    const int tt  = lb % bpb;
    const int m0  = (tt / tilesN) << 8;
    const int n0  = (tt % tilesN) << 8;

    const unsigned short* Ab = A  + (size_t)bat * sA  + (size_t)m0 * K;
    const unsigned short* Bb = BT + (size_t)bat * sBT + (size_t)n0 * K;

    int srow[2], scol[2], lo[2];
#pragma unroll
    for (int r = 0; r < 2; ++r) {
        int c   = r * 512 + t;
        srow[r] = c >> 3;
        scol[r] = ((c & 7) * 8) ^ ((srow[r] & 7) << 3);
        lo[r]   = c * 8;
    }

    auto stageA = [&](int kt, int h) {
        unsigned short* base = Lraw + (kt & 1) * 16384;
#pragma unroll
        for (int r = 0; r < 2; ++r)
            async16(Ab + (size_t)(h * 128 + srow[r]) * K + kt * 64 + scol[r],
                    base + h * 8192 + lo[r]);
    };
    auto stageB = [&](int buf, int kt) {
        unsigned short* base = Lraw + 32768 + buf * 16384;
#pragma unroll
        for (int h = 0; h < 2; ++h)
#pragma unroll
            for (int r = 0; r < 2; ++r)
                async16(Bb + (size_t)(h * 128 + srow[r]) * K + kt * 64 + scol[r],
                        base + h * 8192 + lo[r]);
    };
    auto rdA = [&](int buf, int mf, int kkj) -> bf16x8s {
        int row = wm * 128 + mf * 16 + fr;
        int e   = (kkj * 32 + fk) ^ ((row & 7) << 3);
        return *(const bf16x8s*)&Lraw[buf * 16384 + row * 64 + e];
    };
    auto rdB = [&](int buf, int nf, int kkj) -> bf16x8s {
        int row = wn * 64 + nf * 16 + fr;
        int e   = (kkj * 32 + fk) ^ ((row & 7) << 3);
        return *(const bf16x8s*)&Lraw[32768 + buf * 16384 + row * 64 + e];
    };

    const int nt = K >> 6;

    f32x4 acc[8][4];
#pragma unroll
    for (int i = 0; i < 8; ++i)
#pragma unroll
        for (int j = 0; j < 4; ++j) acc[i][j] = f32x4{0.f, 0.f, 0.f, 0.f};

    bf16x8s aP[4], aB[4], aC[4], bX[4], bY[4];

    stageA(0, 0); stageA(0, 1);
    stageB(0, 0);
    if (nt > 1) {
        stageB(1, 1);
        asm volatile("s_waitcnt vmcnt(4)" ::: "memory");
    } else {
        asm volatile("s_waitcnt vmcnt(0)" ::: "memory");
    }
    __builtin_amdgcn_s_barrier();
#pragma unroll
    for (int m = 0; m < 4; ++m) aP[m] = rdA(0, m, 0);
#pragma unroll
    for (int n = 0; n < 4; ++n) bX[n] = rdB(0, n, 0);

    int bc = 0;
    for (int it = 0; it < nt; ++it) {
        const int cur = it & 1;
        const int bn1 = (bc == 2) ? 0 : bc + 1;
        const int bn2 = (bn1 == 2) ? 0 : bn1 + 1;
        const bool m1 = (it + 1 < nt), m2 = (it + 2 < nt);

        __builtin_amdgcn_s_barrier();
#pragma unroll
        for (int m = 0; m < 4; ++m) aB[m] = rdA(cur, m + 4, 0);
        if (m1) stageA(it + 1, 0);
        __builtin_amdgcn_s_setprio(1);
#pragma unroll
        for (int m = 0; m < 4; ++m)
#pragma unroll
            for (int n = 0; n < 4; ++n) MFMA_(acc[m][n], aP[m], bX[n]);
        __builtin_amdgcn_s_setprio(0);

        __builtin_amdgcn_s_barrier();
#pragma unroll
        for (int m = 0; m < 4; ++m) aC[m] = rdA(cur, m, 1);
#pragma unroll
        for (int n = 0; n < 4; ++n) bY[n] = rdB(bc, n, 1);
        if (m1) stageA(it + 1, 1);
        __builtin_amdgcn_s_setprio(1);
#pragma unroll
        for (int m = 0; m < 4; ++m)
#pragma unroll
            for (int n = 0; n < 4; ++n) MFMA_(acc[m + 4][n], aB[m], bX[n]);
        __builtin_amdgcn_s_setprio(0);

        __builtin_amdgcn_s_barrier();
#pragma unroll
        for (int m = 0; m < 4; ++m) aB[m] = rdA(cur, m + 4, 1);
        if (m2) stageB(bn2, it + 2);
        __builtin_amdgcn_s_setprio(1);
#pragma unroll
        for (int m = 0; m < 4; ++m)
#pragma unroll
            for (int n = 0; n < 4; ++n) MFMA_(acc[m][n], aC[m], bY[n]);
        __builtin_amdgcn_s_setprio(0);

        if (m1) {
            if (m2) asm volatile("s_waitcnt vmcnt(4)" ::: "memory");
            else    asm volatile("s_waitcnt vmcnt(0)" ::: "memory");
            __builtin_amdgcn_s_barrier();
#pragma unroll
            for (int m = 0; m < 4; ++m) aP[m] = rdA(cur ^ 1, m, 0);
#pragma unroll
            for (int n = 0; n < 4; ++n) bX[n] = rdB(bn1, n, 0);
        }
        __builtin_amdgcn_s_setprio(1);
#pragma unroll
        for (int m = 0; m < 4; ++m)
#pragma unroll
            for (int n = 0; n < 4; ++n) MFMA_(acc[m + 4][n], aB[m], bY[n]);
        __builtin_amdgcn_s_setprio(0);
        bc = bn1;
    }

    __syncthreads();

    const int R0 = m0 + wm * 128;
    const int C0 = n0 + wn * 64;
    float bv[4];
#pragma unroll
    for (int j = 0; j < 4; ++j)
        bv[j] = bias ? bias[C0 + j * 16 + fr] : 0.f;

    if (OUT_F32) {
        float* Cb = (float*)Cout + (size_t)bat * sC;
#pragma unroll
        for (int j = 0; j < 4; ++j)
#pragma unroll
            for (int i = 0; i < 8; ++i)
#pragma unroll
                for (int e = 0; e < 4; ++e) {
                    float v = acc[i][j][e] + bv[j];
                    if (RELU) v = fmaxf(v, 0.f);
                    Cb[(size_t)(R0 + i * 16 + r4 + e) * N + C0 + j * 16 + fr] = v;
                }
    } else {
        unsigned short* sl = Lraw + wv * 8192;
#pragma unroll
        for (int i = 0; i < 8; ++i)
#pragma unroll
            for (int j = 0; j < 4; ++j)
#pragma unroll
                for (int e = 0; e < 4; ++e) {
                    float v = acc[i][j][e] + bv[j];
                    if (RELU) v = fmaxf(v, 0.f);
                    const int row = i * 16 + r4 + e;
                    const int col = j * 16 + fr;
                    sl[row * 64 + (col ^ ((row & 7) << 3))] = f2bf(v);
                }
        unsigned short* Cb = (unsigned short*)Cout + (size_t)bat * sC;
#pragma unroll
        for (int rr = 0; rr < 16; ++rr) {
            const int row = rr * 8 + (lane >> 3);
            const int k8  = lane & 7;
            us8 v = *(const us8*)&sl[row * 64 + ((k8 ^ (row & 7)) << 3)];
            *(us8*)&Cb[(size_t)(R0 + row) * N + C0 + k8 * 8] = v;
        }
    }
}

extern "C" void kernel_launch(void* const* d_in, const int* in_sizes, int n_in,
                              void* d_out, int out_size, void* d_ws, size_t ws_size,
                              hipStream_t stream) {
    constexpr int B = 32, N = 1024, F = 512;

    const float* x0f  = (const float*)d_in[0];
    const float* adjf = (const float*)d_in[1];
    const float* W1 = (const float*)d_in[2];
    const float* b1 = (const float*)d_in[3];
    const float* W2 = (const float*)d_in[4];
    const float* b2 = (const float*)d_in[5];
    const float* W3 = (const float*)d_in[6];
    const float* b3 = (const float*)d_in[7];

    unsigned short* ws   = (unsigned short*)d_ws;
    unsigned short* adjb = ws;                           // B*N*N bf16
    unsigned short* P0   = adjb + (size_t)B * N * N;     // B*N*F
    unsigned short* P1   = P0 + (size_t)B * N * F;
    unsigned short* PT   = P1 + (size_t)B * N * F;       // B*F*N
    unsigned short* WT1  = PT + (size_t)B * N * F;
    unsigned short* WT2  = WT1 + (size_t)F * F;
    unsigned short* WT3  = WT2 + (size_t)F * F;

    prep<<<256, 256, 0, stream>>>(W1, W2, W3, WT1, WT2, WT3);

    const int grid = 256;
    const long sX = (long)N * F;
    const long sAd = (long)N * N;

    // layer 1: fused f32-input kernels (x0 direct; adj direct + writeback)
    gemm_g1f<<<grid, 512, 0, stream>>>(WT1, x0f, PT);
    gemm_g2f<<<grid, 512, 0, stream>>>(adjf, adjb, PT, P1, b1);
    // layer 2
    gemm256<false, false><<<grid, 512, 0, stream>>>(WT2,  P1, PT, nullptr, F, N, F, 0,  sX, sX);
    gemm256<true,  false><<<grid, 512, 0, stream>>>(adjb, PT, P0, b2,      N, F, N, sAd, sX, sX);
    // layer 3 (fp32 out, no relu)
    gemm256<false, false><<<grid, 512, 0, stream>>>(WT3,  P0, PT, nullptr, F, N, F, 0,  sX, sX);
    gemm256<false, true ><<<grid, 512, 0, stream>>>(adjb, PT, (float*)d_out, b3, N, F, N, sAd, sX, sX);
}

// Round 12
// 231.497 us; speedup vs baseline: 2.4708x; 1.0325x over previous
//
#include <hip/hip_runtime.h>
#include <hip/hip_bf16.h>

// GCN: 3 x [ relu(A @ (X @ W) + b) ]  (no relu layer 3), fp32 I/O, bf16 MFMA.
// R11: G2f (adj-f32 fused GEMM) gets B TRIPLE-buffering + counted vmcnt(12)
// (never waits on fresh wb-stores / next-next B). G1f: loadB at ph2 + counted
// vmcnt(8). Register-neutral (acc 128 AGPR + ~128 VGPR = 2 waves/SIMD budget).
//   G1: T  = W^T @ X^T : gemm(A=WT [F][F], BT=X [N][F]) -> T [F][N]
//   G2: X' = adj @ T^T : gemm(A=adj [N][N], BT=T [F][N]) -> X' [N][F] (+b,relu)
// Layer 1 consumes f32 inputs directly (reg-stage + pack bf16 + ds_write);
// G2f writes adjb bf16 back (n0==0 blocks) for layers 2/3. prep = W^T only.

typedef __attribute__((ext_vector_type(8))) short bf16x8s;
typedef __attribute__((ext_vector_type(4))) float f32x4;
typedef __attribute__((ext_vector_type(4))) unsigned short us4;
typedef __attribute__((ext_vector_type(8))) unsigned short us8;

__device__ __forceinline__ unsigned short f2bf(float f) {
    unsigned u = __builtin_bit_cast(unsigned, f);
    u += 0x7fffu + ((u >> 16) & 1u);          // RNE
    return (unsigned short)(u >> 16);
}

__device__ __forceinline__ us8 pack8(float4 a, float4 b) {
    us8 o;
    o[0] = f2bf(a.x); o[1] = f2bf(a.y); o[2] = f2bf(a.z); o[3] = f2bf(a.w);
    o[4] = f2bf(b.x); o[5] = f2bf(b.y); o[6] = f2bf(b.z); o[7] = f2bf(b.w);
    return o;
}

__device__ __forceinline__ void async16(const unsigned short* g, unsigned short* l) {
    __builtin_amdgcn_global_load_lds(
        (const __attribute__((address_space(1))) unsigned int*)g,
        (__attribute__((address_space(3))) unsigned int*)l, 16, 0, 0);
}

#define MFMA_(d, va, vb) d = __builtin_amdgcn_mfma_f32_16x16x32_bf16(va, vb, d, 0, 0, 0)

// -------- prep: three W transposes only (3 MB) --------
__global__ void prep(const float* __restrict__ W1, const float* __restrict__ W2,
                     const float* __restrict__ W3, unsigned short* __restrict__ WT1,
                     unsigned short* __restrict__ WT2, unsigned short* __restrict__ WT3) {
    constexpr int F = 512;
    const long FF = (long)F * F;
    const long S = (long)gridDim.x * 256;
    for (long k = (long)blockIdx.x * 256 + threadIdx.x; k < 3 * FF; k += S) {
        int w = (int)(k / FF);
        long idx = k % FF;
        int r = (int)(idx % F);
        int c = (int)(idx / F);
        const float* W = (w == 0) ? W1 : (w == 1) ? W2 : W3;
        unsigned short* WT = (w == 0) ? WT1 : (w == 1) ? WT2 : WT3;
        WT[idx] = f2bf(W[(size_t)r * F + c]);
    }
}

// ================= fused G1 layer-1: PT = WT1 @ X0^T (X0 = f32) =============
__global__ __launch_bounds__(512, 2)
void gemm_g1f(const unsigned short* __restrict__ WT,   // [512][512] bf16
              const float* __restrict__ X0,            // [32][1024][512] f32
              unsigned short* __restrict__ PT)         // [32][512][1024] bf16
{
    constexpr int K = 512, NN = 1024;
    constexpr int nt = K >> 6;                          // 8
    __shared__ unsigned short Lraw[65536];              // A dbuf 64KB | B dbuf 64KB

    const int t = threadIdx.x, lane = t & 63, wv = t >> 6;
    const int wm = wv >> 2, wn = wv & 3;
    const int fr = lane & 15, fk = (lane >> 4) * 8, r4 = (lane >> 4) * 4;
    const int lb = ((int)blockIdx.x & 7) * 32 + ((int)blockIdx.x >> 3);
    const int bat = lb >> 3, tt = lb & 7;
    const int m0 = (tt >> 2) << 8, n0 = (tt & 3) << 8;  // 2 M-tiles x 4 N-tiles

    const unsigned short* Ab = WT + (size_t)m0 * K;
    const float* Bb = X0 + (size_t)bat * NN * K + (size_t)n0 * K;

    int srow[2], scol[2], lo[2];
#pragma unroll
    for (int r = 0; r < 2; ++r) {
        int c   = r * 512 + t;
        srow[r] = c >> 3;
        scol[r] = ((c & 7) * 8) ^ ((srow[r] & 7) << 3);
        lo[r]   = c * 8;
    }

    auto stageA = [&](int kt, int h) {
        unsigned short* base = Lraw + (kt & 1) * 16384;
#pragma unroll
        for (int r = 0; r < 2; ++r)
            async16(Ab + (size_t)(h * 128 + srow[r]) * K + kt * 64 + scol[r],
                    base + h * 8192 + lo[r]);
    };
    auto rdA = [&](int buf, int mf, int kkj) -> bf16x8s {
        int row = wm * 128 + mf * 16 + fr;
        int e   = (kkj * 32 + fk) ^ ((row & 7) << 3);
        return *(const bf16x8s*)&Lraw[buf * 16384 + row * 64 + e];
    };
    auto rdB = [&](int buf, int nf, int kkj) -> bf16x8s {
        int row = wn * 64 + nf * 16 + fr;
        int e   = (kkj * 32 + fk) ^ ((row & 7) << 3);
        return *(const bf16x8s*)&Lraw[32768 + buf * 16384 + row * 64 + e];
    };

    float4 fa[4], fb[4];
    auto loadB = [&](int kt) {
#pragma unroll
        for (int h = 0; h < 2; ++h)
#pragma unroll
            for (int r = 0; r < 2; ++r) {
                const float* p = Bb + (size_t)(h * 128 + srow[r]) * K + kt * 64 + scol[r];
                fa[h * 2 + r] = *(const float4*)p;
                fb[h * 2 + r] = *(const float4*)(p + 4);
            }
    };
    auto writeB = [&](int buf) {
#pragma unroll
        for (int h = 0; h < 2; ++h)
#pragma unroll
            for (int r = 0; r < 2; ++r)
                *(us8*)&Lraw[32768 + buf * 16384 + h * 8192 + lo[r]] =
                    pack8(fa[h * 2 + r], fb[h * 2 + r]);
    };

    f32x4 acc[8][4];
#pragma unroll
    for (int i = 0; i < 8; ++i)
#pragma unroll
        for (int j = 0; j < 4; ++j) acc[i][j] = f32x4{0.f, 0.f, 0.f, 0.f};
    bf16x8s aP[4], aB[4], aC[4], bX[4], bY[4];

    // prologue: B(0) f32->LDS, A(0) async, B(1) f32 in regs
    loadB(0);
    stageA(0, 0); stageA(0, 1);
    writeB(0);                      // compiler waits loadB(0) regs
    loadB(1);
    asm volatile("s_waitcnt vmcnt(8)" ::: "memory");   // A(0) done; loadB(1) flies
    __syncthreads();
#pragma unroll
    for (int m = 0; m < 4; ++m) aP[m] = rdA(0, m, 0);
#pragma unroll
    for (int n = 0; n < 4; ++n) bX[n] = rdB(0, n, 0);

    for (int it = 0; it < nt; ++it) {
        const int cur = it & 1, nxt = cur ^ 1;
        const bool m1 = it + 1 < nt, m2 = it + 2 < nt;

        __builtin_amdgcn_s_barrier();                       // ph0
#pragma unroll
        for (int m = 0; m < 4; ++m) aB[m] = rdA(cur, m + 4, 0);
        if (m1) { stageA(it + 1, 0); stageA(it + 1, 1); }   // 4 asyncs
        __builtin_amdgcn_s_setprio(1);
#pragma unroll
        for (int m = 0; m < 4; ++m)
#pragma unroll
            for (int n = 0; n < 4; ++n) MFMA_(acc[m][n], aP[m], bX[n]);
        __builtin_amdgcn_s_setprio(0);

        __builtin_amdgcn_s_barrier();                       // ph1
#pragma unroll
        for (int m = 0; m < 4; ++m) aC[m] = rdA(cur, m, 1);
#pragma unroll
        for (int n = 0; n < 4; ++n) bY[n] = rdB(cur, n, 1);
        __builtin_amdgcn_s_setprio(1);
#pragma unroll
        for (int m = 0; m < 4; ++m)
#pragma unroll
            for (int n = 0; n < 4; ++n) MFMA_(acc[m + 4][n], aB[m], bX[n]);
        __builtin_amdgcn_s_setprio(0);

        __builtin_amdgcn_s_barrier();                       // ph2
#pragma unroll
        for (int m = 0; m < 4; ++m) aB[m] = rdA(cur, m + 4, 1);
        if (m1) writeB(nxt);                                // cvt + ds_write B(it+1)
        if (m2) loadB(it + 2);                              // 8 f32 loads (after flush)
        __builtin_amdgcn_s_setprio(1);
#pragma unroll
        for (int m = 0; m < 4; ++m)
#pragma unroll
            for (int n = 0; n < 4; ++n) MFMA_(acc[m][n], aC[m], bY[n]);
        __builtin_amdgcn_s_setprio(0);

        if (m1) {                                           // ph3
            // stageA(it+1) done; loadB(it+2) (8, newer) may stay in flight
            if (m2) asm volatile("s_waitcnt vmcnt(8) lgkmcnt(0)" ::: "memory");
            else    asm volatile("s_waitcnt vmcnt(0) lgkmcnt(0)" ::: "memory");
            __builtin_amdgcn_s_barrier();
#pragma unroll
            for (int m = 0; m < 4; ++m) aP[m] = rdA(nxt, m, 0);
#pragma unroll
            for (int n = 0; n < 4; ++n) bX[n] = rdB(nxt, n, 0);
        }
        __builtin_amdgcn_s_setprio(1);
#pragma unroll
        for (int m = 0; m < 4; ++m)
#pragma unroll
            for (int n = 0; n < 4; ++n) MFMA_(acc[m + 4][n], aB[m], bY[n]);
        __builtin_amdgcn_s_setprio(0);
    }

    __syncthreads();
    // epilogue: LDS bounce -> us8 coalesced stores, PT row-major [512][1024]
    const int R0 = m0 + wm * 128;
    const int C0 = n0 + wn * 64;
    unsigned short* sl = Lraw + wv * 8192;
#pragma unroll
    for (int i = 0; i < 8; ++i)
#pragma unroll
        for (int j = 0; j < 4; ++j)
#pragma unroll
            for (int e = 0; e < 4; ++e) {
                const int row = i * 16 + r4 + e;
                const int col = j * 16 + fr;
                sl[row * 64 + (col ^ ((row & 7) << 3))] = f2bf(acc[i][j][e]);
            }
    unsigned short* Cb = PT + (size_t)bat * 512 * 1024;
#pragma unroll
    for (int rr = 0; rr < 16; ++rr) {
        const int row = rr * 8 + (lane >> 3);
        const int k8  = lane & 7;
        us8 v = *(const us8*)&sl[row * 64 + ((k8 ^ (row & 7)) << 3)];
        *(us8*)&Cb[(size_t)(R0 + row) * NN + C0 + k8 * 8] = v;
    }
}

// ====== fused G2 layer-1: P1 = relu(adj @ PT^T + b1), adj f32 + writeback ===
// B (PT) triple-buffered, staged 2 tiles ahead; counted vmcnt(12) at ph3.
__global__ __launch_bounds__(512, 2)
void gemm_g2f(const float* __restrict__ ADJ,            // [32][1024][1024] f32
              unsigned short* __restrict__ adjb,        // bf16 out (plain layout)
              const unsigned short* __restrict__ PT,    // [32][512][1024] bf16
              unsigned short* __restrict__ P1,          // [32][1024][512] bf16
              const float* __restrict__ bias)
{
    constexpr int K = 1024, NN = 512;
    constexpr int nt = K >> 6;                          // 16
    // 160 KiB: A dbuf 2x16384 | B tripbuf 3x16384 (elems)
    __shared__ unsigned short Lraw[81920];

    const int t = threadIdx.x, lane = t & 63, wv = t >> 6;
    const int wm = wv >> 2, wn = wv & 3;
    const int fr = lane & 15, fk = (lane >> 4) * 8, r4 = (lane >> 4) * 4;
    const int lb = ((int)blockIdx.x & 7) * 32 + ((int)blockIdx.x >> 3);
    const int bat = lb >> 3, tt = lb & 7;
    const int m0 = (tt >> 1) << 8, n0 = (tt & 1) << 8;  // 4 M-tiles x 2 N-tiles
    const bool wb = (n0 == 0);

    const float* Afb = ADJ + (size_t)bat * K * K + (size_t)m0 * K;
    unsigned short* Awb = adjb + (size_t)bat * K * K + (size_t)m0 * K;
    const unsigned short* Bb = PT + (size_t)bat * NN * K + (size_t)n0 * K;

    int srow[2], scol[2], lo[2];
#pragma unroll
    for (int r = 0; r < 2; ++r) {
        int c   = r * 512 + t;
        srow[r] = c >> 3;
        scol[r] = ((c & 7) * 8) ^ ((srow[r] & 7) << 3);
        lo[r]   = c * 8;
    }

    auto stageB = [&](int buf, int kt) {                // both halves, 4 asyncs
        unsigned short* base = Lraw + 32768 + buf * 16384;
#pragma unroll
        for (int h = 0; h < 2; ++h)
#pragma unroll
            for (int r = 0; r < 2; ++r)
                async16(Bb + (size_t)(h * 128 + srow[r]) * K + kt * 64 + scol[r],
                        base + h * 8192 + lo[r]);
    };
    auto rdA = [&](int buf, int mf, int kkj) -> bf16x8s {
        int row = wm * 128 + mf * 16 + fr;
        int e   = (kkj * 32 + fk) ^ ((row & 7) << 3);
        return *(const bf16x8s*)&Lraw[buf * 16384 + row * 64 + e];
    };
    auto rdB = [&](int buf, int nf, int kkj) -> bf16x8s {
        int row = wn * 64 + nf * 16 + fr;
        int e   = (kkj * 32 + fk) ^ ((row & 7) << 3);
        return *(const bf16x8s*)&Lraw[32768 + buf * 16384 + row * 64 + e];
    };

    float4 fa[4], fb[4];
    auto loadA = [&](int kt) {
#pragma unroll
        for (int h = 0; h < 2; ++h)
#pragma unroll
            for (int r = 0; r < 2; ++r) {
                const float* p = Afb + (size_t)(h * 128 + srow[r]) * K + kt * 64 + scol[r];
                fa[h * 2 + r] = *(const float4*)p;
                fb[h * 2 + r] = *(const float4*)(p + 4);
            }
    };
    auto flushA = [&](int buf, int kt) {                // cvt + ds_write + writeback
#pragma unroll
        for (int h = 0; h < 2; ++h)
#pragma unroll
            for (int r = 0; r < 2; ++r) {
                us8 v = pack8(fa[h * 2 + r], fb[h * 2 + r]);
                *(us8*)&Lraw[buf * 16384 + h * 8192 + lo[r]] = v;
                if (wb)
                    *(us8*)&Awb[(size_t)(h * 128 + srow[r]) * K + kt * 64 + scol[r]] = v;
            }
    };

    f32x4 acc[8][4];
#pragma unroll
    for (int i = 0; i < 8; ++i)
#pragma unroll
        for (int j = 0; j < 4; ++j) acc[i][j] = f32x4{0.f, 0.f, 0.f, 0.f};
    bf16x8s aP[4], aB[4], aC[4], bX[4], bY[4];

    // prologue: A(0) f32->LDS(+wb), A(1) in regs, B(0)/B(1) async
    loadA(0);
    stageB(0, 0); stageB(1, 1);
    flushA(0, 0);                   // compiler waits loadA(0) regs
    loadA(1);
    asm volatile("s_waitcnt vmcnt(4)" ::: "memory");   // B(0) done (conservative)
    __syncthreads();
#pragma unroll
    for (int m = 0; m < 4; ++m) aP[m] = rdA(0, m, 0);
#pragma unroll
    for (int n = 0; n < 4; ++n) bX[n] = rdB(0, n, 0);

    int bc = 0;                     // B buffer of current tile
    for (int it = 0; it < nt; ++it) {
        const int cur = it & 1, nxt = cur ^ 1;
        const int bn1 = (bc == 2) ? 0 : bc + 1;
        const int bn2 = (bn1 == 2) ? 0 : bn1 + 1;
        const bool m1 = it + 1 < nt, m2 = it + 2 < nt;

        __builtin_amdgcn_s_barrier();                       // ph0
#pragma unroll
        for (int m = 0; m < 4; ++m) aB[m] = rdA(cur, m + 4, 0);
        __builtin_amdgcn_s_setprio(1);
#pragma unroll
        for (int m = 0; m < 4; ++m)
#pragma unroll
            for (int n = 0; n < 4; ++n) MFMA_(acc[m][n], aP[m], bX[n]);
        __builtin_amdgcn_s_setprio(0);

        __builtin_amdgcn_s_barrier();                       // ph1
#pragma unroll
        for (int m = 0; m < 4; ++m) aC[m] = rdA(cur, m, 1);
#pragma unroll
        for (int n = 0; n < 4; ++n) bY[n] = rdB(bc, n, 1);
        __builtin_amdgcn_s_setprio(1);
#pragma unroll
        for (int m = 0; m < 4; ++m)
#pragma unroll
            for (int n = 0; n < 4; ++n) MFMA_(acc[m + 4][n], aB[m], bX[n]);
        __builtin_amdgcn_s_setprio(0);

        __builtin_amdgcn_s_barrier();                       // ph2
#pragma unroll
        for (int m = 0; m < 4; ++m) aB[m] = rdA(cur, m + 4, 1);
        if (m1) flushA(nxt, it + 1);                        // ds_write + wb stores
        if (m2) stageB(bn2, it + 2);                        // 4 asyncs (newest)
        __builtin_amdgcn_s_setprio(1);
#pragma unroll
        for (int m = 0; m < 4; ++m)
#pragma unroll
            for (int n = 0; n < 4; ++n) MFMA_(acc[m][n], aC[m], bY[n]);
        __builtin_amdgcn_s_setprio(0);

        if (m1) {                                           // ph3
            // need stageB(it+1) landed (issued ph2 of it-1 / prologue).
            // newer ops: loadA(it+1..) 8 + wb stores 8 + stageB(it+2) 4 = 12 async-visible
            if (m2) asm volatile("s_waitcnt vmcnt(12) lgkmcnt(0)" ::: "memory");
            else    asm volatile("s_waitcnt vmcnt(0) lgkmcnt(0)" ::: "memory");
            __builtin_amdgcn_s_barrier();
#pragma unroll
            for (int m = 0; m < 4; ++m) aP[m] = rdA(nxt, m, 0);
#pragma unroll
            for (int n = 0; n < 4; ++n) bX[n] = rdB(bn1, n, 0);
            if (m2) loadA(it + 2);                          // 8 f32 loads
        }
        __builtin_amdgcn_s_setprio(1);
#pragma unroll
        for (int m = 0; m < 4; ++m)
#pragma unroll
            for (int n = 0; n < 4; ++n) MFMA_(acc[m + 4][n], aB[m], bY[n]);
        __builtin_amdgcn_s_setprio(0);
        bc = bn1;
    }

    __syncthreads();
    // epilogue: bias + relu, LDS bounce, P1 row-major [1024][512]
    const int R0 = m0 + wm * 128;
    const int C0 = n0 + wn * 64;
    float bv[4];
#pragma unroll
    for (int j = 0; j < 4; ++j) bv[j] = bias[C0 + j * 16 + fr];
    unsigned short* sl = Lraw + wv * 8192;
#pragma unroll
    for (int i = 0; i < 8; ++i)
#pragma unroll
        for (int j = 0; j < 4; ++j)
#pragma unroll
            for (int e = 0; e < 4; ++e) {
                const int row = i * 16 + r4 + e;
                const int col = j * 16 + fr;
                sl[row * 64 + (col ^ ((row & 7) << 3))] =
                    f2bf(fmaxf(acc[i][j][e] + bv[j], 0.f));
            }
    unsigned short* Cb = P1 + (size_t)bat * 1024 * 512;
#pragma unroll
    for (int rr = 0; rr < 16; ++rr) {
        const int row = rr * 8 + (lane >> 3);
        const int k8  = lane & 7;
        us8 v = *(const us8*)&sl[row * 64 + ((k8 ^ (row & 7)) << 3)];
        *(us8*)&Cb[(size_t)(R0 + row) * NN + C0 + k8 * 8] = v;
    }
}

// ================= R8 core (unchanged) for the 4 bf16 GEMMs =================
template<bool RELU, bool OUT_F32>
__global__ __launch_bounds__(512, 2)
void gemm256(const unsigned short* __restrict__ A,
             const unsigned short* __restrict__ BT,
             void* __restrict__ Cout,
             const float* __restrict__ bias,
             int M, int N, int K,
             long sA, long sBT, long sC)
{
    __shared__ unsigned short Lraw[81920];

    const int t    = threadIdx.x;
    const int lane = t & 63;
    const int wv   = t >> 6;
    const int wm   = wv >> 2;
    const int wn   = wv & 3;
    const int fr   = lane & 15;
    const int fk   = (lane >> 4) * 8;
    const int r4   = (lane >> 4) * 4;

    const int tilesN = N >> 8;
    const int bpb    = (M >> 8) * tilesN;
    const int cpx = gridDim.x >> 3;
    const int lb  = (blockIdx.x & 7) * cpx + (blockIdx.x >> 3);
    const int bat = lb / bpb;
    const int tt  = lb % bpb;
    const int m0  = (tt / tilesN) << 8;
    const int n0  = (tt % tilesN) << 8;

    const unsigned short* Ab = A  + (size_t)bat * sA  + (size_t)m0 * K;
    const unsigned short* Bb = BT + (size_t)bat * sBT + (size_t)n0 * K;

    int srow[2], scol[2], lo[2];
#pragma unroll
    for (int r = 0; r < 2; ++r) {
        int c   = r * 512 + t;
        srow[r] = c >> 3;
        scol[r] = ((c & 7) * 8) ^ ((srow[r] & 7) << 3);
        lo[r]   = c * 8;
    }

    auto stageA = [&](int kt, int h) {
        unsigned short* base = Lraw + (kt & 1) * 16384;
#pragma unroll
        for (int r = 0; r < 2; ++r)
            async16(Ab + (size_t)(h * 128 + srow[r]) * K + kt * 64 + scol[r],
                    base + h * 8192 + lo[r]);
    };
    auto stageB = [&](int buf, int kt) {
        unsigned short* base = Lraw + 32768 + buf * 16384;
#pragma unroll
        for (int h = 0; h < 2; ++h)
#pragma unroll
            for (int r = 0; r < 2; ++r)
                async16(Bb + (size_t)(h * 128 + srow[r]) * K + kt * 64 + scol[r],
                        base + h * 8192 + lo[r]);
    };
    auto rdA = [&](int buf, int mf, int kkj) -> bf16x8s {
        int row = wm * 128 + mf * 16 + fr;
        int e   = (kkj * 32 + fk) ^ ((row & 7) << 3);
        return *(const bf16x8s*)&Lraw[buf * 16384 + row * 64 + e];
    };
    auto rdB = [&](int buf, int nf, int kkj) -> bf16x8s {
        int row = wn * 64 + nf * 16 + fr;
        int e   = (kkj * 32 + fk) ^ ((row & 7) << 3);
        return *(const bf16x8s*)&Lraw[32768 + buf * 16384 + row * 64 + e];
    };

    const int nt = K >> 6;

    f32x4 acc[8][4];
#pragma unroll
    for (int i = 0; i < 8; ++i)
#pragma unroll
        for (int j = 0; j < 4; ++j) acc[i][j] = f32x4{0.f, 0.f, 0.f, 0.f};

    bf16x8s aP[4], aB[4], aC[4], bX[4], bY[4];

    stageA(0, 0); stageA(0, 1);
    stageB(0, 0);
    if (nt > 1) {
        stageB(1, 1);
        asm volatile("s_waitcnt vmcnt(4)" ::: "memory");
    } else {
        asm volatile("s_waitcnt vmcnt(0)" ::: "memory");
    }
    __builtin_amdgcn_s_barrier();
#pragma unroll
    for (int m = 0; m < 4; ++m) aP[m] = rdA(0, m, 0);
#pragma unroll
    for (int n = 0; n < 4; ++n) bX[n] = rdB(0, n, 0);

    int bc = 0;
    for (int it = 0; it < nt; ++it) {
        const int cur = it & 1;
        const int bn1 = (bc == 2) ? 0 : bc + 1;
        const int bn2 = (bn1 == 2) ? 0 : bn1 + 1;
        const bool m1 = (it + 1 < nt), m2 = (it + 2 < nt);

        __builtin_amdgcn_s_barrier();
#pragma unroll
        for (int m = 0; m < 4; ++m) aB[m] = rdA(cur, m + 4, 0);
        if (m1) stageA(it + 1, 0);
        __builtin_amdgcn_s_setprio(1);
#pragma unroll
        for (int m = 0; m < 4; ++m)
#pragma unroll
            for (int n = 0; n < 4; ++n) MFMA_(acc[m][n], aP[m], bX[n]);
        __builtin_amdgcn_s_setprio(0);

        __builtin_amdgcn_s_barrier();
#pragma unroll
        for (int m = 0; m < 4; ++m) aC[m] = rdA(cur, m, 1);
#pragma unroll
        for (int n = 0; n < 4; ++n) bY[n] = rdB(bc, n, 1);
        if (m1) stageA(it + 1, 1);
        __builtin_amdgcn_s_setprio(1);
#pragma unroll
        for (int m = 0; m < 4; ++m)
#pragma unroll
            for (int n = 0; n < 4; ++n) MFMA_(acc[m + 4][n], aB[m], bX[n]);
        __builtin_amdgcn_s_setprio(0);

        __builtin_amdgcn_s_barrier();
#pragma unroll
        for (int m = 0; m < 4; ++m) aB[m] = rdA(cur, m + 4, 1);
        if (m2) stageB(bn2, it + 2);
        __builtin_amdgcn_s_setprio(1);
#pragma unroll
        for (int m = 0; m < 4; ++m)
#pragma unroll
            for (int n = 0; n < 4; ++n) MFMA_(acc[m][n], aC[m], bY[n]);
        __builtin_amdgcn_s_setprio(0);

        if (m1) {
            if (m2) asm volatile("s_waitcnt vmcnt(4)" ::: "memory");
            else    asm volatile("s_waitcnt vmcnt(0)" ::: "memory");
            __builtin_amdgcn_s_barrier();
#pragma unroll
            for (int m = 0; m < 4; ++m) aP[m] = rdA(cur ^ 1, m, 0);
#pragma unroll
            for (int n = 0; n < 4; ++n) bX[n] = rdB(bn1, n, 0);
        }
        __builtin_amdgcn_s_setprio(1);
#pragma unroll
        for (int m = 0; m < 4; ++m)
#pragma unroll
            for (int n = 0; n < 4; ++n) MFMA_(acc[m + 4][n], aB[m], bY[n]);
        __builtin_amdgcn_s_setprio(0);
        bc = bn1;
    }

    __syncthreads();

    const int R0 = m0 + wm * 128;
    const int C0 = n0 + wn * 64;
    float bv[4];
#pragma unroll
    for (int j = 0; j < 4; ++j)
        bv[j] = bias ? bias[C0 + j * 16 + fr] : 0.f;

    if (OUT_F32) {
        float* Cb = (float*)Cout + (size_t)bat * sC;
#pragma unroll
        for (int j = 0; j < 4; ++j)
#pragma unroll
            for (int i = 0; i < 8; ++i)
#pragma unroll
                for (int e = 0; e < 4; ++e) {
                    float v = acc[i][j][e] + bv[j];
                    if (RELU) v = fmaxf(v, 0.f);
                    Cb[(size_t)(R0 + i * 16 + r4 + e) * N + C0 + j * 16 + fr] = v;
                }
    } else {
        unsigned short* sl = Lraw + wv * 8192;
#pragma unroll
        for (int i = 0; i < 8; ++i)
#pragma unroll
            for (int j = 0; j < 4; ++j)
#pragma unroll
                for (int e = 0; e < 4; ++e) {
                    float v = acc[i][j][e] + bv[j];
                    if (RELU) v = fmaxf(v, 0.f);
                    const int row = i * 16 + r4 + e;
                    const int col = j * 16 + fr;
                    sl[row * 64 + (col ^ ((row & 7) << 3))] = f2bf(v);
                }
        unsigned short* Cb = (unsigned short*)Cout + (size_t)bat * sC;
#pragma unroll
        for (int rr = 0; rr < 16; ++rr) {
            const int row = rr * 8 + (lane >> 3);
            const int k8  = lane & 7;
            us8 v = *(const us8*)&sl[row * 64 + ((k8 ^ (row & 7)) << 3)];
            *(us8*)&Cb[(size_t)(R0 + row) * N + C0 + k8 * 8] = v;
        }
    }
}

extern "C" void kernel_launch(void* const* d_in, const int* in_sizes, int n_in,
                              void* d_out, int out_size, void* d_ws, size_t ws_size,
                              hipStream_t stream) {
    constexpr int B = 32, N = 1024, F = 512;

    const float* x0f  = (const float*)d_in[0];
    const float* adjf = (const float*)d_in[1];
    const float* W1 = (const float*)d_in[2];
    const float* b1 = (const float*)d_in[3];
    const float* W2 = (const float*)d_in[4];
    const float* b2 = (const float*)d_in[5];
    const float* W3 = (const float*)d_in[6];
    const float* b3 = (const float*)d_in[7];

    unsigned short* ws   = (unsigned short*)d_ws;
    unsigned short* adjb = ws;                           // B*N*N bf16
    unsigned short* P0   = adjb + (size_t)B * N * N;     // B*N*F
    unsigned short* P1   = P0 + (size_t)B * N * F;
    unsigned short* PT   = P1 + (size_t)B * N * F;       // B*F*N
    unsigned short* WT1  = PT + (size_t)B * N * F;
    unsigned short* WT2  = WT1 + (size_t)F * F;
    unsigned short* WT3  = WT2 + (size_t)F * F;

    prep<<<256, 256, 0, stream>>>(W1, W2, W3, WT1, WT2, WT3);

    const int grid = 256;
    const long sX = (long)N * F;
    const long sAd = (long)N * N;

    // layer 1: fused f32-input kernels (x0 direct; adj direct + writeback)
    gemm_g1f<<<grid, 512, 0, stream>>>(WT1, x0f, PT);
    gemm_g2f<<<grid, 512, 0, stream>>>(adjf, adjb, PT, P1, b1);
    // layer 2
    gemm256<false, false><<<grid, 512, 0, stream>>>(WT2,  P1, PT, nullptr, F, N, F, 0,  sX, sX);
    gemm256<true,  false><<<grid, 512, 0, stream>>>(adjb, PT, P0, b2,      N, F, N, sAd, sX, sX);
    // layer 3 (fp32 out, no relu)
    gemm256<false, false><<<grid, 512, 0, stream>>>(WT3,  P0, PT, nullptr, F, N, F, 0,  sX, sX);
    gemm256<false, true ><<<grid, 512, 0, stream>>>(adjb, PT, (float*)d_out, b3, N, F, N, sAd, sX, sX);
}